// Round 2
// baseline (1569.009 us; speedup 1.0000x reference)
//
#include <hip/hip_runtime.h>
#include <hip/hip_bf16.h>

typedef unsigned short ushort_t;
typedef unsigned int uint_t;

#define BB 16
#define TE 128
#define TD 64
#define HH 256
#define G3 768
#define KK 256
#define OUTV 32000
#define MROWS_E (BB*TE)   // 2048
#define MROWS_D (BB*TD)   // 1024

typedef __attribute__((ext_vector_type(8))) short short8;
typedef __attribute__((ext_vector_type(4))) float f32x4;

__device__ __forceinline__ float b2f(ushort_t u) {
  union { uint_t i; float f; } v; v.i = ((uint_t)u) << 16; return v.f;
}
__device__ __forceinline__ ushort_t f2b(float f) {
  union { float f; uint_t i; } v; v.f = f;
  uint_t x = v.i;
  return (ushort_t)((x + 0x7fffu + ((x >> 16) & 1u)) >> 16);
}
// dtype-adaptive scalar load of a "float" input: f32f!=0 -> fp32 buffer, else bf16
__device__ __forceinline__ float ldf(const void* p, size_t i, uint_t f32f) {
  return f32f ? ((const float*)p)[i] : b2f(((const ushort_t*)p)[i]);
}
// fast, saturating sigmoid/tanh (inputs bounded; formulas robust at +-inf)
__device__ __forceinline__ float fsig(float x) { return 1.f/(1.f + __expf(-x)); }
__device__ __forceinline__ float ftanh(float x) { return 1.f - 2.f/(__expf(2.f*x) + 1.f); }

// async global->LDS, 16B per lane. Dest must be contiguous in lane order.
__device__ __forceinline__ void gload_lds16(const void* g, void* l) {
  __builtin_amdgcn_global_load_lds(
      (const __attribute__((address_space(1))) unsigned int*)g,
      (__attribute__((address_space(3))) unsigned int*)l, 16, 0, 0);
}

// ---------------------------------------------------------------------------
// dtype detector (fp32 on this harness; kept for safety).
// ---------------------------------------------------------------------------
__global__ __launch_bounds__(256) void detect_kernel(const void* emb, uint_t* flag) {
  int tid = threadIdx.x;
  uint_t w = ((const uint_t*)emb)[tid];
  uint_t e = (w >> 7) & 0xFFu;
  bool pass = (e >= 100u && e <= 127u);
  unsigned long long m = __ballot(pass);
  __shared__ int cnt[4];
  if ((tid & 63) == 0) cnt[tid >> 6] = __popcll(m);
  __syncthreads();
  if (tid == 0) {
    int c = cnt[0] + cnt[1] + cnt[2] + cnt[3];
    *flag = (c >= 128) ? 0u : 1u;
  }
}

// ---------------------------------------------------------------------------
// prep: Whh -> bf16 [768][256]; dense_W -> bf16 transpose; combined gi biases
// (bih + bhh folded for r,z gates -> GRU needn't add them); out bias -> fp32.
// ---------------------------------------------------------------------------
__global__ __launch_bounds__(256) void prep_kernel(
    const void* eWhh, const void* dWhh, const void* denseW,
    const void* ebih, const void* ebhh, const void* dbih, const void* dbhh,
    const void* outb, const uint_t* flagp,
    ushort_t* WBe, ushort_t* WBd, ushort_t* DWT,
    float* cbe, float* cbd, float* obf) {
  uint_t f = *flagp;
  int tid = blockIdx.x * blockDim.x + threadIdx.x;
  int nth = gridDim.x * blockDim.x;
  for (int i = tid; i < G3*KK; i += nth) {
    WBe[i] = f2b(ldf(eWhh, i, f));
    WBd[i] = f2b(ldf(dWhh, i, f));
  }
  for (int i = tid; i < 512*HH; i += nth) {
    int k = i / HH, c = i % HH;
    DWT[i] = f2b(ldf(denseW, (size_t)c*512 + k, f));
  }
  for (int i = tid; i < G3; i += nth) {
    float be = ldf(ebih, i, f), bd = ldf(dbih, i, f);
    if (i < 2*HH) { be += ldf(ebhh, i, f); bd += ldf(dbhh, i, f); }
    cbe[i] = be; cbd[i] = bd;
  }
  for (int i = tid; i < OUTV; i += nth) obf[i] = ldf(outb, i, f);
}

// ---------------------------------------------------------------------------
// Generic MFMA GEMM: C[m][n] = sum_k A[m][k]*B[n][k] (+bias[n]), K=256 fixed.
// tshift!=0: output rows remapped m=(b*T+t) -> t*BB+b with T=1<<tshift.
// a_f32!=0: ws A operand is fp32 (converted to bf16 during staging).
// bias (if non-null) is always fp32 (prep-produced).
// ---------------------------------------------------------------------------
#define LDT 264

__global__ __launch_bounds__(256) void gemm_kernel(
    const ushort_t* A, const int* tokens, const void* emb,
    const void* Bw, int ldb, int b_off,
    const float* bias, const uint_t* flagp,
    float* Cf, ushort_t* Cb, int ldc, int M, int tshift, int a_f32) {
  __shared__ __align__(16) ushort_t Bs[64*LDT];
  __shared__ __align__(16) ushort_t As[32*LDT];
  uint_t f = *flagp;
  int tid = threadIdx.x;
  int wave = tid >> 6, lane = tid & 63;
  int n0 = blockIdx.x * 64;
#pragma unroll
  for (int it = 0; it < 8; ++it) {
    int idx = it*256 + tid;
    int row = idx >> 5, col = (idx & 31) << 3;
    size_t e = (size_t)(n0 + row)*ldb + col + b_off;
    uint4 v;
    if (f) {
      const float4* s = (const float4*)((const float*)Bw + e);
      float4 x = s[0], y = s[1];
      v.x = (uint_t)f2b(x.x) | ((uint_t)f2b(x.y) << 16);
      v.y = (uint_t)f2b(x.z) | ((uint_t)f2b(x.w) << 16);
      v.z = (uint_t)f2b(y.x) | ((uint_t)f2b(y.y) << 16);
      v.w = (uint_t)f2b(y.z) | ((uint_t)f2b(y.w) << 16);
    } else {
      v = *(const uint4*)((const ushort_t*)Bw + e);
    }
    *(uint4*)(Bs + row*LDT + col) = v;
  }
  int arow_i = lane & 15;
  float bias_v = 0.f;
  if (bias) bias_v = bias[n0 + wave*16 + arow_i];
  int koff = (lane >> 4) << 3;
  for (int m0 = blockIdx.y*32; m0 < M; m0 += gridDim.y*32) {
    __syncthreads();   // Bs ready / previous chunk compute done
#pragma unroll
    for (int it = 0; it < 4; ++it) {
      int idx = it*256 + tid;
      int row = idx >> 5, col = (idx & 31) << 3;
      uint4 v;
      if (tokens) {
        size_t e = (size_t)tokens[m0 + row]*KK + col;
        if (f) {
          const float4* s = (const float4*)((const float*)emb + e);
          float4 x = s[0], y = s[1];
          v.x = (uint_t)f2b(x.x) | ((uint_t)f2b(x.y) << 16);
          v.y = (uint_t)f2b(x.z) | ((uint_t)f2b(x.w) << 16);
          v.z = (uint_t)f2b(y.x) | ((uint_t)f2b(y.y) << 16);
          v.w = (uint_t)f2b(y.z) | ((uint_t)f2b(y.w) << 16);
        } else {
          v = *(const uint4*)((const ushort_t*)emb + e);
        }
      } else if (a_f32) {
        const float4* s = (const float4*)((const float*)A + (size_t)(m0 + row)*KK + col);
        float4 x = s[0], y = s[1];
        v.x = (uint_t)f2b(x.x) | ((uint_t)f2b(x.y) << 16);
        v.y = (uint_t)f2b(x.z) | ((uint_t)f2b(x.w) << 16);
        v.z = (uint_t)f2b(y.x) | ((uint_t)f2b(y.y) << 16);
        v.w = (uint_t)f2b(y.z) | ((uint_t)f2b(y.w) << 16);
      } else {
        v = *(const uint4*)(A + (size_t)(m0 + row)*KK + col);  // ws bf16
      }
      *(uint4*)(As + row*LDT + col) = v;
    }
    __syncthreads();
#pragma unroll
    for (int msub = 0; msub < 2; ++msub) {
      f32x4 acc = {0.f,0.f,0.f,0.f};
      const ushort_t* ap = As + (msub*16 + arow_i)*LDT + koff;
      const ushort_t* bp = Bs + (wave*16 + arow_i)*LDT + koff;
#pragma unroll
      for (int ks = 0; ks < 8; ++ks) {
        short8 af = *(const short8*)(ap + ks*32);
        short8 bf = *(const short8*)(bp + ks*32);
        acc = __builtin_amdgcn_mfma_f32_16x16x32_bf16(af, bf, acc, 0, 0, 0);
      }
      int mbase = m0 + msub*16 + (lane >> 4)*4;
      int ncol = n0 + wave*16 + arow_i;
#pragma unroll
      for (int r = 0; r < 4; ++r) {
        float val = acc[r] + bias_v;
        int mr = mbase + r;
        int orow = tshift ? (((mr & ((1 << tshift) - 1)) << 4) + (mr >> tshift)) : mr;
        if (Cf) Cf[(size_t)orow*ldc + ncol] = val;
        else    Cb[(size_t)orow*ldc + ncol] = f2b(val);
      }
    }
  }
}

// ---------------------------------------------------------------------------
// MFMA GRU: ONE block, 256 threads (4 waves, 1 wave/SIMD -> 512-reg unified
// cap per wave via __launch_bounds__(256,1)).
//
// ROUND-1 POST-MORTEM: with 512 threads (2 waves/SIMD, 256-reg cap) the
// 192-reg Whh fragment set + ~70 working regs never fit; allocator collapsed
// to 128 VGPRs and spilled everything (VALUBusy 43%/CU of accvgpr/scratch
// traffic). Structural fix: 4 waves x 1/SIMD -> 512 regs/wave. Each wave owns
// 64 hidden cols x 3 gates = 12 MFMA tiles: bfrag 3x4x8 short8 = 384 regs
// (MFMA-B operands, AGPR-eligible) + acc 48 + hreg 16 + ~40 working ~= 490.
// A-fragment (h) loaded once per k-slice, shared by all 12 tiles. All LDS
// addressing is lane-const base + compile-time immediate offsets.
// ---------------------------------------------------------------------------
#define HSBF 264            // h_bf row stride (bf16); 528B = 33*16 (b128 ok)
#define HBUF (BB*HSBF)      // 4224 shorts = 8448 B per buffer
#define GILDS 772           // gi row stride (fp32); 3088B = 193*16
#define GIBUF (BB*GILDS)    // 12352 floats = 49408 B per buffer

__device__ __forceinline__ void stage_gi(const float* gi, int t, float* sbuf,
                                         int wave, int lane) {
#pragma unroll
  for (int rr = 0; rr < 4; ++rr) {
    int m = wave*4 + rr;
    const float* src = gi + ((size_t)t*BB + m)*G3 + lane*4;
    float* dst = sbuf + m*GILDS + lane*4;
#pragma unroll
    for (int rd = 0; rd < 3; ++rd)
      gload_lds16(src + rd*256, dst + rd*256);
  }
}

__device__ __forceinline__ void gru_phase(
    const float* gi, const ushort_t* WB, const void* bhh, const int* lens,
    uint_t f, const int T, float* out,
    float* gi_lds, ushort_t* h_bf, float (&hreg)[16], bool init_h)
{
  int tid = threadIdx.x;
  int wave = tid >> 6, lane = tid & 63;
  int mrow = lane & 15, quad = lane >> 4;
  // register-resident Whh fragments: wave owns cols j in [64w, 64w+64):
  // gate g, col-tile tc -> B rows g*256 + 64w + 16tc + mrow
  short8 bfrag[3][4][8];
#pragma unroll
  for (int g = 0; g < 3; ++g)
#pragma unroll
    for (int tc = 0; tc < 4; ++tc) {
      const ushort_t* wb = WB + (size_t)(g*HH + wave*64 + tc*16 + mrow)*KK + (quad << 3);
#pragma unroll
      for (int ks = 0; ks < 8; ++ks)
        bfrag[g][tc][ks] = *(const short8*)(wb + ks*32);
    }
  // only the n-gate hidden bias is applied in-kernel (r,z folded into gi)
  float bias_n[4];
#pragma unroll
  for (int tc = 0; tc < 4; ++tc)
    bias_n[tc] = ldf(bhh, 2*HH + wave*64 + tc*16 + mrow, f);
  int len_r[4];
#pragma unroll
  for (int r = 0; r < 4; ++r) len_r[r] = lens[quad*4 + r];
  if (init_h) {
#pragma unroll
    for (int i = 0; i < 16; ++i) hreg[i] = 0.f;
    for (int i = tid; i < HBUF; i += 256) h_bf[i] = 0;   // buffer 0 only
  }
  stage_gi(gi, 0, gi_lds, wave, lane);
  __syncthreads();   // h_bf[0] + gi buf[0] ready (vmcnt drained by barrier)
  for (int t = 0; t < T; ++t) {
    const float* gbuf = gi_lds + (t & 1)*GIBUF;
    float* sbuf = gi_lds + ((t + 1) & 1)*GIBUF;
    const ushort_t* hb_r = h_bf + (t & 1)*HBUF;
    ushort_t* hb_w = h_bf + ((t + 1) & 1)*HBUF;
    if (t + 1 < T) stage_gi(gi, t + 1, sbuf, wave, lane);
    // ---- MFMA: 12 tiles, one shared A-fragment per k-slice --------------
    const ushort_t* hb = hb_r + mrow*HSBF + (quad << 3);
    f32x4 acc[3][4];
#pragma unroll
    for (int g = 0; g < 3; ++g)
#pragma unroll
      for (int tc = 0; tc < 4; ++tc) acc[g][tc] = (f32x4){0.f,0.f,0.f,0.f};
#pragma unroll
    for (int ks = 0; ks < 8; ++ks) {
      short8 av = *(const short8*)(hb + ks*32);
#pragma unroll
      for (int g = 0; g < 3; ++g)
#pragma unroll
        for (int tc = 0; tc < 4; ++tc)
          acc[g][tc] = __builtin_amdgcn_mfma_f32_16x16x32_bf16(
              av, bfrag[g][tc][ks], acc[g][tc], 0, 0, 0);
    }
    // ---- elementwise: lane owns 16 (m=quad*4+r, j=64w+16tc+mrow) --------
    const float* gq = gbuf + quad*(4*GILDS) + wave*64 + mrow;
    ushort_t* hw = hb_w + quad*(4*HSBF) + wave*64 + mrow;
    float* op = out + (size_t)(quad*4)*T*HH + (size_t)t*HH + wave*64 + mrow;
#pragma unroll
    for (int tc = 0; tc < 4; ++tc) {
      float bn = bias_n[tc];
#pragma unroll
      for (int r = 0; r < 4; ++r) {
        float rr = fsig(gq[r*GILDS + tc*16]          + acc[0][tc][r]);
        float zz = fsig(gq[r*GILDS + tc*16 + HH]     + acc[1][tc][r]);
        float nn = ftanh(gq[r*GILDS + tc*16 + 2*HH] + rr*(acc[2][tc][r] + bn));
        float hold = hreg[tc*4 + r];
        float hc = (1.f - zz)*nn + zz*hold;
        bool valid = t < len_r[r];
        float ov = valid ? hc : 0.f;
        float hnew = valid ? hc : hold;
        op[(size_t)r*(T*HH) + tc*16] = ov;
        hreg[tc*4 + r] = hnew;
        hw[r*HSBF + tc*16] = f2b(hnew);
      }
    }
    __syncthreads();   // h_bf[1-p] + gi buf for t+1 ready for next step
  }
}

__global__ __launch_bounds__(256, 1) void gru_kernel(
    const float* gi_e, const float* gi_d, const ushort_t* WBe, const ushort_t* WBd,
    const void* ebhh, const void* dbhh, const uint_t* flagp,
    const int* elen, const int* dlen, float* eout, float* dout) {
  uint_t f = *flagp;
  __shared__ __align__(16) float gi_lds[2*GIBUF];    // 98816 B
  __shared__ __align__(16) ushort_t h_bf[2*HBUF];    // 16896 B
  float hreg[16];
  gru_phase(gi_e, WBe, ebhh, elen, f, TE, eout, gi_lds, h_bf, hreg, true);
  // TE=128 even -> encoder's final h landed in h_bf buffer 0; decoder reads it.
  gru_phase(gi_d, WBd, dbhh, dlen, f, TD, dout, gi_lds, h_bf, hreg, false);
}

// ---------------------------------------------------------------------------
// Attention + dense, one block per (b, td). (unchanged)
// ---------------------------------------------------------------------------
__global__ __launch_bounds__(256) void attn_kernel(
    const float* eprj, const float* dprj, const float* eout, const float* dout,
    const void* Wb, const void* av, const void* avb,
    const ushort_t* DWT, const void* db, const uint_t* flagp,
    const int* elen, const int* dlen, ushort_t* dense_bf) {
  int bd = blockIdx.x;
  int b = bd / TD, td = bd % TD;
  int tid = threadIdx.x;
  int wave = tid >> 6, lane = tid & 63;
  uint_t f = *flagp;
  __shared__ float dp[HH], dsrow[HH], vv[HH], att[TE];
  int el = elen[b];
  bool dok = td < dlen[b];
  size_t drow = (size_t)bd * HH;
  dp[tid] = dprj[drow + tid] + ldf(Wb, tid, f);
  dsrow[tid] = dout[drow + tid];
  vv[tid] = ldf(av, tid, f);
  __syncthreads();
  float vb0 = ldf(avb, 0, f);
  for (int teb = 0; teb < TE/4; ++teb) {
    int te = teb*4 + wave;
    float e = -1e30f;
    if (dok && te < el) {
      const float* ep = eprj + (size_t)(b*TE + te)*HH;
      float s = 0.f;
#pragma unroll
      for (int i = 0; i < 4; ++i) {
        int hh = lane + 64*i;
        s += tanhf(ep[hh] + dp[hh]) * vv[hh];
      }
#pragma unroll
      for (int off = 32; off > 0; off >>= 1) s += __shfl_xor(s, off);
      e = s + vb0;
    }
    if (lane == 0) att[te] = e;
  }
  __syncthreads();
  float m = -1e30f;
  for (int te = 0; te < TE; ++te) m = fmaxf(m, att[te]);
  __syncthreads();
  if (tid < TE) {
    float e = att[tid];
    att[tid] = (e > -1e29f) ? expf(e - m) : 0.f;
  }
  __syncthreads();
  float ssum = 0.f;
  for (int te = 0; te < TE; ++te) ssum += att[te];
  float inv = (ssum > 0.f) ? 1.f/ssum : 0.f;
  float c = 0.f;
  for (int te = 0; te < TE; ++te) {
    float wgt = att[te];
    if (wgt > 0.f) c += wgt * eout[(size_t)(b*TE + te)*HH + tid];
  }
  c *= inv;
  __syncthreads();
  dp[tid] = c;   // reuse dp as context
  __syncthreads();
  float acc = ldf(db, tid, f);
#pragma unroll 4
  for (int k = 0; k < HH; ++k) acc = fmaf(b2f(DWT[k*HH + tid]), dsrow[k], acc);
#pragma unroll 4
  for (int k = 0; k < HH; ++k) acc = fmaf(b2f(DWT[(HH + k)*HH + tid]), dp[k], acc);
  dense_bf[drow + tid] = f2b(tanhf(acc));
}

// ---------------------------------------------------------------------------
extern "C" void kernel_launch(void* const* d_in, const int* in_sizes, int n_in,
                              void* d_out, int out_size, void* d_ws, size_t ws_size,
                              hipStream_t stream) {
  const int* enc_in   = (const int*)d_in[0];
  const int* enc_len  = (const int*)d_in[1];
  const int* dec_in   = (const int*)d_in[2];
  const int* dec_len  = (const int*)d_in[3];
  const void* emb    = d_in[4];
  const void* eWih   = d_in[5];
  const void* eWhh   = d_in[6];
  const void* ebih   = d_in[7];
  const void* ebhh   = d_in[8];
  const void* dWih   = d_in[9];
  const void* dWhh   = d_in[10];
  const void* dbih   = d_in[11];
  const void* dbhh   = d_in[12];
  const void* attnW  = d_in[13];
  const void* attnWb = d_in[14];
  const void* attnv  = d_in[15];
  const void* attnvb = d_in[16];
  const void* denseW = d_in[17];
  const void* denseb = d_in[18];
  const void* outW   = d_in[19];
  const void* outb   = d_in[20];
  float* out = (float*)d_out;   // reference output is fp32

  float* ws = (float*)d_ws;
  size_t o = 0;
  uint_t* flag = (uint_t*)(ws + o);   o += 4;
  ushort_t* WBe = (ushort_t*)(ws + o); o += G3*KK/2;
  ushort_t* WBd = (ushort_t*)(ws + o); o += G3*KK/2;
  ushort_t* DWT = (ushort_t*)(ws + o); o += 512*HH/2;
  float* cbe = ws + o;                o += G3;
  float* cbd = ws + o;                o += G3;
  float* obf = ws + o;                o += OUTV;
  float* gi_e = ws + o;               o += (size_t)MROWS_E*G3;   // (t,b)-interleaved
  float* gi_d = ws + o;               o += (size_t)MROWS_D*G3;   // (t,b)-interleaved
  float* eout = ws + o;               o += (size_t)MROWS_E*HH;
  float* dout = ws + o;               o += (size_t)MROWS_D*HH;
  float* eprj = ws + o;               o += (size_t)MROWS_E*HH;
  float* dprj = ws + o;               o += (size_t)MROWS_D*HH;
  ushort_t* dense_bf = (ushort_t*)(ws + o); o += (size_t)MROWS_D*HH/2;

  detect_kernel<<<1, 256, 0, stream>>>(emb, flag);
  prep_kernel<<<384, 256, 0, stream>>>(eWhh, dWhh, denseW, ebih, ebhh, dbih, dbhh,
                                       outb, flag, WBe, WBd, DWT, cbe, cbd, obf);
  // gi = emb[tokens] @ Wih.T + (bih + bhh[r,z]), rows (t,b)-interleaved
  gemm_kernel<<<dim3(12,8), 256, 0, stream>>>(nullptr, enc_in, emb, eWih, 256, 0,
                                              cbe, flag, gi_e, nullptr, G3, MROWS_E, 7, 0);
  gemm_kernel<<<dim3(12,4), 256, 0, stream>>>(nullptr, dec_in, emb, dWih, 256, 0,
                                              cbd, flag, gi_d, nullptr, G3, MROWS_D, 6, 0);
  gru_kernel<<<1, 256, 0, stream>>>(gi_e, gi_d, WBe, WBd, ebhh, dbhh, flag,
                                    enc_len, dec_len, eout, dout);
  // enc_proj = enc_out @ W1.T ; dec_proj = dec_out @ W2.T  (attn_W col split)
  gemm_kernel<<<dim3(4,16), 256, 0, stream>>>((const ushort_t*)eout, nullptr, nullptr,
                                              attnW, 512, 0, nullptr, flag, eprj,
                                              nullptr, HH, MROWS_E, 0, 1);
  gemm_kernel<<<dim3(4,8), 256, 0, stream>>>((const ushort_t*)dout, nullptr, nullptr,
                                             attnW, 512, 256, nullptr, flag, dprj,
                                             nullptr, HH, MROWS_D, 0, 1);
  attn_kernel<<<MROWS_D, 256, 0, stream>>>(eprj, dprj, eout, dout, attnWb, attnv, attnvb,
                                           DWT, denseb, flag, enc_len, dec_len, dense_bf);
  // logits = dense @ out_W.T + out_b  (fp32 out)
  gemm_kernel<<<dim3(500,4), 256, 0, stream>>>(dense_bf, nullptr, nullptr, outW, 256, 0,
                                               obf, flag, out, nullptr, OUTV, MROWS_D, 0, 0);
}

// Round 4
// 1180.087 us; speedup vs baseline: 1.3296x; 1.3296x over previous
//
#include <hip/hip_runtime.h>
#include <hip/hip_bf16.h>

typedef unsigned short ushort_t;
typedef unsigned int uint_t;

#define BB 16
#define TE 128
#define TD 64
#define HH 256
#define G3 768
#define KK 256
#define OUTV 32000
#define MROWS_E (BB*TE)   // 2048
#define MROWS_D (BB*TD)   // 1024
#define NBLK 16           // GRU blocks (CUs); each owns JD h-dims
#define JD 16

typedef __attribute__((ext_vector_type(8))) short short8;
typedef __attribute__((ext_vector_type(4))) float f32x4;

__device__ __forceinline__ float b2f(ushort_t u) {
  union { uint_t i; float f; } v; v.i = ((uint_t)u) << 16; return v.f;
}
__device__ __forceinline__ ushort_t f2b(float f) {
  union { float f; uint_t i; } v; v.f = f;
  uint_t x = v.i;
  return (ushort_t)((x + 0x7fffu + ((x >> 16) & 1u)) >> 16);
}
// dtype-adaptive scalar load of a "float" input: f32f!=0 -> fp32 buffer, else bf16
__device__ __forceinline__ float ldf(const void* p, size_t i, uint_t f32f) {
  return f32f ? ((const float*)p)[i] : b2f(((const ushort_t*)p)[i]);
}
// fast, saturating sigmoid/tanh (inputs bounded; formulas robust at +-inf)
__device__ __forceinline__ float fsig(float x) { return 1.f/(1.f + __expf(-x)); }
__device__ __forceinline__ float ftanh(float x) { return 1.f - 2.f/(__expf(2.f*x) + 1.f); }

// ---------------------------------------------------------------------------
// dtype detector (fp32 on this harness; kept for safety).
// ---------------------------------------------------------------------------
__global__ __launch_bounds__(256) void detect_kernel(const void* emb, uint_t* flag) {
  int tid = threadIdx.x;
  uint_t w = ((const uint_t*)emb)[tid];
  uint_t e = (w >> 7) & 0xFFu;
  bool pass = (e >= 100u && e <= 127u);
  unsigned long long m = __ballot(pass);
  __shared__ int cnt[4];
  if ((tid & 63) == 0) cnt[tid >> 6] = __popcll(m);
  __syncthreads();
  if (tid == 0) {
    int c = cnt[0] + cnt[1] + cnt[2] + cnt[3];
    *flag = (c >= 128) ? 0u : 1u;
  }
}

// ---------------------------------------------------------------------------
// prep: Whh -> bf16 [768][256]; dense_W -> bf16 transpose; combined gi biases
// (bih + bhh folded for r,z gates); out bias -> fp32; zero h-exchange buffer
// and the GRU grid barrier counter (re-zeroed every invocation/replay).
// ---------------------------------------------------------------------------
__global__ __launch_bounds__(256) void prep_kernel(
    const void* eWhh, const void* dWhh, const void* denseW,
    const void* ebih, const void* ebhh, const void* dbih, const void* dbhh,
    const void* outb, const uint_t* flagp,
    ushort_t* WBe, ushort_t* WBd, ushort_t* DWT,
    float* cbe, float* cbd, float* obf,
    uint_t* hbuf, uint_t* bar) {
  uint_t f = *flagp;
  int tid = blockIdx.x * blockDim.x + threadIdx.x;
  int nth = gridDim.x * blockDim.x;
  for (int i = tid; i < G3*KK; i += nth) {
    WBe[i] = f2b(ldf(eWhh, i, f));
    WBd[i] = f2b(ldf(dWhh, i, f));
  }
  for (int i = tid; i < 512*HH; i += nth) {
    int k = i / HH, c = i % HH;
    DWT[i] = f2b(ldf(denseW, (size_t)c*512 + k, f));
  }
  for (int i = tid; i < G3; i += nth) {
    float be = ldf(ebih, i, f), bd = ldf(dbih, i, f);
    if (i < 2*HH) { be += ldf(ebhh, i, f); bd += ldf(dbhh, i, f); }
    cbe[i] = be; cbd[i] = bd;
  }
  for (int i = tid; i < OUTV; i += nth) obf[i] = ldf(outb, i, f);
  for (int i = tid; i < 4096; i += nth) hbuf[i] = 0;   // both h buffers
  if (tid == 0) *bar = 0;
}

// ---------------------------------------------------------------------------
// Generic MFMA GEMM: C[m][n] = sum_k A[m][k]*B[n][k] (+bias[n]), K=256 fixed.
// tshift!=0: output rows remapped m=(b*T+t) -> t*BB+b with T=1<<tshift.
// a_f32!=0: ws A operand is fp32 (converted to bf16 during staging).
// bias (if non-null) is always fp32 (prep-produced).
// ---------------------------------------------------------------------------
#define LDT 264

__global__ __launch_bounds__(256) void gemm_kernel(
    const ushort_t* A, const int* tokens, const void* emb,
    const void* Bw, int ldb, int b_off,
    const float* bias, const uint_t* flagp,
    float* Cf, ushort_t* Cb, int ldc, int M, int tshift, int a_f32) {
  __shared__ __align__(16) ushort_t Bs[64*LDT];
  __shared__ __align__(16) ushort_t As[32*LDT];
  uint_t f = *flagp;
  int tid = threadIdx.x;
  int wave = tid >> 6, lane = tid & 63;
  int n0 = blockIdx.x * 64;
#pragma unroll
  for (int it = 0; it < 8; ++it) {
    int idx = it*256 + tid;
    int row = idx >> 5, col = (idx & 31) << 3;
    size_t e = (size_t)(n0 + row)*ldb + col + b_off;
    uint4 v;
    if (f) {
      const float4* s = (const float4*)((const float*)Bw + e);
      float4 x = s[0], y = s[1];
      v.x = (uint_t)f2b(x.x) | ((uint_t)f2b(x.y) << 16);
      v.y = (uint_t)f2b(x.z) | ((uint_t)f2b(x.w) << 16);
      v.z = (uint_t)f2b(y.x) | ((uint_t)f2b(y.y) << 16);
      v.w = (uint_t)f2b(y.z) | ((uint_t)f2b(y.w) << 16);
    } else {
      v = *(const uint4*)((const ushort_t*)Bw + e);
    }
    *(uint4*)(Bs + row*LDT + col) = v;
  }
  int arow_i = lane & 15;
  float bias_v = 0.f;
  if (bias) bias_v = bias[n0 + wave*16 + arow_i];
  int koff = (lane >> 4) << 3;
  for (int m0 = blockIdx.y*32; m0 < M; m0 += gridDim.y*32) {
    __syncthreads();   // Bs ready / previous chunk compute done
#pragma unroll
    for (int it = 0; it < 4; ++it) {
      int idx = it*256 + tid;
      int row = idx >> 5, col = (idx & 31) << 3;
      uint4 v;
      if (tokens) {
        size_t e = (size_t)tokens[m0 + row]*KK + col;
        if (f) {
          const float4* s = (const float4*)((const float*)emb + e);
          float4 x = s[0], y = s[1];
          v.x = (uint_t)f2b(x.x) | ((uint_t)f2b(x.y) << 16);
          v.y = (uint_t)f2b(x.z) | ((uint_t)f2b(x.w) << 16);
          v.z = (uint_t)f2b(y.x) | ((uint_t)f2b(y.y) << 16);
          v.w = (uint_t)f2b(y.z) | ((uint_t)f2b(y.w) << 16);
        } else {
          v = *(const uint4*)((const ushort_t*)emb + e);
        }
      } else if (a_f32) {
        const float4* s = (const float4*)((const float*)A + (size_t)(m0 + row)*KK + col);
        float4 x = s[0], y = s[1];
        v.x = (uint_t)f2b(x.x) | ((uint_t)f2b(x.y) << 16);
        v.y = (uint_t)f2b(x.z) | ((uint_t)f2b(x.w) << 16);
        v.z = (uint_t)f2b(y.x) | ((uint_t)f2b(y.y) << 16);
        v.w = (uint_t)f2b(y.z) | ((uint_t)f2b(y.w) << 16);
      } else {
        v = *(const uint4*)(A + (size_t)(m0 + row)*KK + col);  // ws bf16
      }
      *(uint4*)(As + row*LDT + col) = v;
    }
    __syncthreads();
#pragma unroll
    for (int msub = 0; msub < 2; ++msub) {
      f32x4 acc = {0.f,0.f,0.f,0.f};
      const ushort_t* ap = As + (msub*16 + arow_i)*LDT + koff;
      const ushort_t* bp = Bs + (wave*16 + arow_i)*LDT + koff;
#pragma unroll
      for (int ks = 0; ks < 8; ++ks) {
        short8 af = *(const short8*)(ap + ks*32);
        short8 bf = *(const short8*)(bp + ks*32);
        acc = __builtin_amdgcn_mfma_f32_16x16x32_bf16(af, bf, acc, 0, 0, 0);
      }
      int mbase = m0 + msub*16 + (lane >> 4)*4;
      int ncol = n0 + wave*16 + arow_i;
#pragma unroll
      for (int r = 0; r < 4; ++r) {
        float val = acc[r] + bias_v;
        int mr = mbase + r;
        int orow = tshift ? (((mr & ((1 << tshift) - 1)) << 4) + (mr >> tshift)) : mr;
        if (Cf) Cf[(size_t)orow*ldc + ncol] = val;
        else    Cb[(size_t)orow*ldc + ncol] = f2b(val);
      }
    }
  }
}

// ---------------------------------------------------------------------------
// Multi-CU MFMA GRU: NBLK=16 blocks x 256 threads. Block k owns h-dims
// [16k,16k+16): its 48 gate rows of Whh (24 KB bf16) are LDS-RESIDENT --
// removes the 384 KB/step L2 weight re-stream that capped single-CU versions
// (weights fit neither registers (384 > 256-reg cap) nor one CU's LDS).
//
// Per step: 6 MFMAs/wave (M=16,N=48, K=256 split 4-way) -> LDS reduce ->
// elementwise (16 dims) -> publish packed-bf16 h-slice to a double-buffered
// global buffer with agent-scope atomics -> bounded-spin counter barrier.
// Race-freedom: block Y enters step s+1 (writing buf[(s+2)&1]) only after
// ALL blocks arrived at s+1, i.e. finished reading buf[s&1]. __syncthreads
// before the arrive drains vmcnt (publish stores complete at the coherent
// point); an agent acquire fence after fan-out guarantees fresh hbuf reads.
// HARDENING (round 4): spin is BOUNDED (~2 ms) so a broken protocol yields
// a completed wrong-answer run with counters instead of a dead container.
// ---------------------------------------------------------------------------
#define HSBF 264            // LDS row stride (bf16 elems): <=2-way banks on b128

__device__ __forceinline__ void stage_w(const ushort_t* WB, int j0, int tid,
                                        ushort_t* wlds) {
#pragma unroll
  for (int it = 0; it < 6; ++it) {
    int idx = it*256 + tid;
    int row = idx >> 5, col = (idx & 31) << 3;   // row 0..47, col 0..255 step 8
    const ushort_t* src = WB + ((size_t)((row >> 4)*HH + j0 + (row & 15)))*KK + col;
    *(uint4*)(wlds + row*HSBF + col) = *(const uint4*)src;
  }
}

__global__ __launch_bounds__(256) void gru_kernel(
    const float* gi_e, const float* gi_d, const ushort_t* WBe, const ushort_t* WBd,
    const void* ebhh, const void* dbhh, const uint_t* flagp,
    const int* elen, const int* dlen, float* eout, float* dout,
    uint_t* hbuf, uint_t* bar) {
  uint_t f = *flagp;
  __shared__ __align__(16) ushort_t wlds[48*HSBF];      // 24.75 KB
  __shared__ __align__(16) float part[4][3][16][17];    // 12.75 KB
  const int tid = threadIdx.x;
  const int wave = tid >> 6, lane = tid & 63;
  const int mrow = lane & 15, quad = lane >> 4;          // MFMA fragment coords
  const int j0 = blockIdx.x * JD;
  const int m = tid >> 4, n = tid & 15;                  // elementwise coords
  const int j = j0 + n;

  stage_w(WBe, j0, tid, wlds);
  const float bn_e = ldf(ebhh, 2*HH + j, f);
  const float bn_d = ldf(dbhh, 2*HH + j, f);
  const int len_e = elen[m], len_d = dlen[m];
  float hreg = 0.f;
  // prefetch gi for s=0 (rows are (t,b)-interleaved: (t*BB+m))
  float grv = gi_e[(size_t)m*G3 + j];
  float gzv = gi_e[(size_t)m*G3 + HH + j];
  float gnv = gi_e[(size_t)m*G3 + 2*HH + j];
  __syncthreads();   // weights staged

  for (int s = 0; s < TE + TD; ++s) {
    if (s == TE) {   // encoder->decoder: restage weights (prev-step sync
                     // ordered the last encoder reads of wlds)
      stage_w(WBd, j0, tid, wlds);
      __syncthreads();
    }
    const bool enc = s < TE;
    const int t = enc ? s : s - TE;
    // ---- A-fragment: full h (packed bf16 pairs) via coherent-point loads --
    const uint_t* hbR = hbuf + (s & 1)*2048;
    uint_t hv[8];
#pragma unroll
    for (int ks = 0; ks < 2; ++ks)
#pragma unroll
      for (int i = 0; i < 4; ++i)
        hv[ks*4 + i] = __hip_atomic_load(
            hbR + mrow*128 + wave*32 + ks*16 + quad*4 + i,
            __ATOMIC_RELAXED, __HIP_MEMORY_SCOPE_AGENT);
    // ---- MFMA: 3 gate tiles, wave's K-slice = [64*wave, 64*wave+64) ------
    f32x4 ar = {0.f,0.f,0.f,0.f}, az = {0.f,0.f,0.f,0.f}, an = {0.f,0.f,0.f,0.f};
#pragma unroll
    for (int ks = 0; ks < 2; ++ks) {
      union { uint_t u[4]; short8 s8; } av;
#pragma unroll
      for (int i = 0; i < 4; ++i) av.u[i] = hv[ks*4 + i];
      const ushort_t* wp = wlds + mrow*HSBF + wave*64 + ks*32 + quad*8;
      short8 b0 = *(const short8*)(wp);
      short8 b1 = *(const short8*)(wp + 16*HSBF);
      short8 b2 = *(const short8*)(wp + 32*HSBF);
      ar = __builtin_amdgcn_mfma_f32_16x16x32_bf16(av.s8, b0, ar, 0, 0, 0);
      az = __builtin_amdgcn_mfma_f32_16x16x32_bf16(av.s8, b1, az, 0, 0, 0);
      an = __builtin_amdgcn_mfma_f32_16x16x32_bf16(av.s8, b2, an, 0, 0, 0);
    }
    // ---- partial store: C-frag row=quad*4+r (m), col=mrow (n) -------------
#pragma unroll
    for (int r = 0; r < 4; ++r) {
      part[wave][0][quad*4 + r][mrow] = ar[r];
      part[wave][1][quad*4 + r][mrow] = az[r];
      part[wave][2][quad*4 + r][mrow] = an[r];
    }
    __syncthreads();
    // ---- reduce K-partials + elementwise (thread owns (m, j)) ------------
    float accr = 0.f, accz = 0.f, accn = 0.f;
#pragma unroll
    for (int w = 0; w < 4; ++w) {
      accr += part[w][0][m][n];
      accz += part[w][1][m][n];
      accn += part[w][2][m][n];
    }
    float rr = fsig(grv + accr);                    // bih+bhh pre-folded in gi
    float zz = fsig(gzv + accz);
    float nn = ftanh(gnv + rr*(accn + (enc ? bn_e : bn_d)));
    float hc = (1.f - zz)*nn + zz*hreg;
    bool valid = t < (enc ? len_e : len_d);
    float ov = valid ? hc : 0.f;
    hreg = valid ? hc : hreg;
    if (enc) eout[((size_t)(m*TE + t))*HH + j] = ov;
    else     dout[((size_t)(m*TD + t))*HH + j] = ov;
    // ---- publish h-slice: packed bf16 pair per even lane -----------------
    uint_t h16 = (uint_t)f2b(hreg);
    uint_t up = (uint_t)__shfl_down((int)h16, 1);
    if (!(n & 1)) {
      __hip_atomic_store(hbuf + ((s + 1) & 1)*2048 + m*128 + (j >> 1),
                         h16 | (up << 16),
                         __ATOMIC_RELAXED, __HIP_MEMORY_SCOPE_AGENT);
    }
    // ---- prefetch next step's gi (independent of barrier) ----------------
    int s2 = s + 1;
    if (s2 < TE + TD) {
      const float* g2 = (s2 < TE) ? (gi_e + (size_t)(s2*BB + m)*G3)
                                  : (gi_d + (size_t)((s2 - TE)*BB + m)*G3);
      grv = g2[j]; gzv = g2[HH + j]; gnv = g2[2*HH + j];
    }
    __syncthreads();   // drains vmcnt per wave: publish stores complete
    if (tid == 0) {
      __hip_atomic_fetch_add(bar, 1u, __ATOMIC_RELEASE, __HIP_MEMORY_SCOPE_AGENT);
      uint_t target = (uint_t)(s + 1) * NBLK;
      int guard = 0;
      while (__hip_atomic_load(bar, __ATOMIC_ACQUIRE, __HIP_MEMORY_SCOPE_AGENT) < target
             && guard < 40000) {        // bounded: ~2 ms >> genuine wait (<10 us)
        __builtin_amdgcn_s_sleep(2);
        ++guard;
      }
    }
    __syncthreads();   // fan-out: all threads see step-(s+1) h as published
    __builtin_amdgcn_fence(__ATOMIC_ACQUIRE, "agent");   // fresh hbuf reads
  }
}

// ---------------------------------------------------------------------------
// Attention + dense, one block per (b, td). (unchanged)
// ---------------------------------------------------------------------------
__global__ __launch_bounds__(256) void attn_kernel(
    const float* eprj, const float* dprj, const float* eout, const float* dout,
    const void* Wb, const void* av, const void* avb,
    const ushort_t* DWT, const void* db, const uint_t* flagp,
    const int* elen, const int* dlen, ushort_t* dense_bf) {
  int bd = blockIdx.x;
  int b = bd / TD, td = bd % TD;
  int tid = threadIdx.x;
  int wave = tid >> 6, lane = tid & 63;
  uint_t f = *flagp;
  __shared__ float dp[HH], dsrow[HH], vv[HH], att[TE];
  int el = elen[b];
  bool dok = td < dlen[b];
  size_t drow = (size_t)bd * HH;
  dp[tid] = dprj[drow + tid] + ldf(Wb, tid, f);
  dsrow[tid] = dout[drow + tid];
  vv[tid] = ldf(av, tid, f);
  __syncthreads();
  float vb0 = ldf(avb, 0, f);
  for (int teb = 0; teb < TE/4; ++teb) {
    int te = teb*4 + wave;
    float e = -1e30f;
    if (dok && te < el) {
      const float* ep = eprj + (size_t)(b*TE + te)*HH;
      float s = 0.f;
#pragma unroll
      for (int i = 0; i < 4; ++i) {
        int hh = lane + 64*i;
        s += tanhf(ep[hh] + dp[hh]) * vv[hh];
      }
#pragma unroll
      for (int off = 32; off > 0; off >>= 1) s += __shfl_xor(s, off);
      e = s + vb0;
    }
    if (lane == 0) att[te] = e;
  }
  __syncthreads();
  float m = -1e30f;
  for (int te = 0; te < TE; ++te) m = fmaxf(m, att[te]);
  __syncthreads();
  if (tid < TE) {
    float e = att[tid];
    att[tid] = (e > -1e29f) ? expf(e - m) : 0.f;
  }
  __syncthreads();
  float ssum = 0.f;
  for (int te = 0; te < TE; ++te) ssum += att[te];
  float inv = (ssum > 0.f) ? 1.f/ssum : 0.f;
  float c = 0.f;
  for (int te = 0; te < TE; ++te) {
    float wgt = att[te];
    if (wgt > 0.f) c += wgt * eout[(size_t)(b*TE + te)*HH + tid];
  }
  c *= inv;
  __syncthreads();
  dp[tid] = c;   // reuse dp as context
  __syncthreads();
  float acc = ldf(db, tid, f);
#pragma unroll 4
  for (int k = 0; k < HH; ++k) acc = fmaf(b2f(DWT[k*HH + tid]), dsrow[k], acc);
#pragma unroll 4
  for (int k = 0; k < HH; ++k) acc = fmaf(b2f(DWT[(HH + k)*HH + tid]), dp[k], acc);
  dense_bf[drow + tid] = f2b(tanhf(acc));
}

// ---------------------------------------------------------------------------
extern "C" void kernel_launch(void* const* d_in, const int* in_sizes, int n_in,
                              void* d_out, int out_size, void* d_ws, size_t ws_size,
                              hipStream_t stream) {
  const int* enc_in   = (const int*)d_in[0];
  const int* enc_len  = (const int*)d_in[1];
  const int* dec_in   = (const int*)d_in[2];
  const int* dec_len  = (const int*)d_in[3];
  const void* emb    = d_in[4];
  const void* eWih   = d_in[5];
  const void* eWhh   = d_in[6];
  const void* ebih   = d_in[7];
  const void* ebhh   = d_in[8];
  const void* dWih   = d_in[9];
  const void* dWhh   = d_in[10];
  const void* dbih   = d_in[11];
  const void* dbhh   = d_in[12];
  const void* attnW  = d_in[13];
  const void* attnWb = d_in[14];
  const void* attnv  = d_in[15];
  const void* attnvb = d_in[16];
  const void* denseW = d_in[17];
  const void* denseb = d_in[18];
  const void* outW   = d_in[19];
  const void* outb   = d_in[20];
  float* out = (float*)d_out;   // reference output is fp32

  float* ws = (float*)d_ws;
  size_t o = 0;
  uint_t* flag = (uint_t*)(ws + o);   o += 4;
  uint_t* hbuf = (uint_t*)(ws + o);   o += 4096;   // 2 x (16x128) packed bf16 pairs
  uint_t* bar  = (uint_t*)(ws + o);   o += 32;     // barrier counter (own line)
  ushort_t* WBe = (ushort_t*)(ws + o); o += G3*KK/2;
  ushort_t* WBd = (ushort_t*)(ws + o); o += G3*KK/2;
  ushort_t* DWT = (ushort_t*)(ws + o); o += 512*HH/2;
  float* cbe = ws + o;                o += G3;
  float* cbd = ws + o;                o += G3;
  float* obf = ws + o;                o += OUTV;
  float* gi_e = ws + o;               o += (size_t)MROWS_E*G3;   // (t,b)-interleaved
  float* gi_d = ws + o;               o += (size_t)MROWS_D*G3;   // (t,b)-interleaved
  float* eout = ws + o;               o += (size_t)MROWS_E*HH;
  float* dout = ws + o;               o += (size_t)MROWS_D*HH;
  float* eprj = ws + o;               o += (size_t)MROWS_E*HH;
  float* dprj = ws + o;               o += (size_t)MROWS_D*HH;
  ushort_t* dense_bf = (ushort_t*)(ws + o); o += (size_t)MROWS_D*HH/2;

  detect_kernel<<<1, 256, 0, stream>>>(emb, flag);
  prep_kernel<<<384, 256, 0, stream>>>(eWhh, dWhh, denseW, ebih, ebhh, dbih, dbhh,
                                       outb, flag, WBe, WBd, DWT, cbe, cbd, obf,
                                       hbuf, bar);
  // gi = emb[tokens] @ Wih.T + (bih + bhh[r,z]), rows (t,b)-interleaved
  gemm_kernel<<<dim3(12,8), 256, 0, stream>>>(nullptr, enc_in, emb, eWih, 256, 0,
                                              cbe, flag, gi_e, nullptr, G3, MROWS_E, 7, 0);
  gemm_kernel<<<dim3(12,4), 256, 0, stream>>>(nullptr, dec_in, emb, dWih, 256, 0,
                                              cbd, flag, gi_d, nullptr, G3, MROWS_D, 6, 0);
  gru_kernel<<<NBLK, 256, 0, stream>>>(gi_e, gi_d, WBe, WBd, ebhh, dbhh, flag,
                                       enc_len, dec_len, eout, dout, hbuf, bar);
  // enc_proj = enc_out @ W1.T ; dec_proj = dec_out @ W2.T  (attn_W col split)
  gemm_kernel<<<dim3(4,16), 256, 0, stream>>>((const ushort_t*)eout, nullptr, nullptr,
                                              attnW, 512, 0, nullptr, flag, eprj,
                                              nullptr, HH, MROWS_E, 0, 1);
  gemm_kernel<<<dim3(4,8), 256, 0, stream>>>((const ushort_t*)dout, nullptr, nullptr,
                                             attnW, 512, 256, nullptr, flag, dprj,
                                             nullptr, HH, MROWS_D, 0, 1);
  attn_kernel<<<MROWS_D, 256, 0, stream>>>(eprj, dprj, eout, dout, attnWb, attnv, attnvb,
                                           DWT, denseb, flag, enc_len, dec_len, dense_bf);
  // logits = dense @ out_W.T + out_b  (fp32 out)
  gemm_kernel<<<dim3(500,4), 256, 0, stream>>>(dense_bf, nullptr, nullptr, outW, 256, 0,
                                               obf, flag, out, nullptr, OUTV, MROWS_D, 0, 0);
}

// Round 5
// 954.388 us; speedup vs baseline: 1.6440x; 1.2365x over previous
//
#include <hip/hip_runtime.h>
#include <hip/hip_bf16.h>

typedef unsigned short ushort_t;
typedef unsigned int uint_t;
typedef unsigned long long u64_t;

#define BB 16
#define TE 128
#define TD 64
#define HH 256
#define G3 768
#define KK 256
#define OUTV 32000
#define MROWS_E (BB*TE)   // 2048
#define MROWS_D (BB*TD)   // 1024
#define NBLK 16           // GRU blocks (CUs); each owns JD h-dims
#define JD 16
#define QW_PER_BUF 2048   // 16 rows x 128 qwords ({2xbf16, tag} words)

typedef __attribute__((ext_vector_type(8))) short short8;
typedef __attribute__((ext_vector_type(4))) float f32x4;

__device__ __forceinline__ float b2f(ushort_t u) {
  union { uint_t i; float f; } v; v.i = ((uint_t)u) << 16; return v.f;
}
__device__ __forceinline__ ushort_t f2b(float f) {
  union { float f; uint_t i; } v; v.f = f;
  uint_t x = v.i;
  return (ushort_t)((x + 0x7fffu + ((x >> 16) & 1u)) >> 16);
}
// dtype-adaptive scalar load of a "float" input: f32f!=0 -> fp32 buffer, else bf16
__device__ __forceinline__ float ldf(const void* p, size_t i, uint_t f32f) {
  return f32f ? ((const float*)p)[i] : b2f(((const ushort_t*)p)[i]);
}
// fast, saturating sigmoid/tanh (inputs bounded; formulas robust at +-inf)
__device__ __forceinline__ float fsig(float x) { return 1.f/(1.f + __expf(-x)); }
__device__ __forceinline__ float ftanh(float x) { return 1.f - 2.f/(__expf(2.f*x) + 1.f); }

// ---------------------------------------------------------------------------
// dtype detector (fp32 on this harness; kept for safety).
// ---------------------------------------------------------------------------
__global__ __launch_bounds__(256) void detect_kernel(const void* emb, uint_t* flag) {
  int tid = threadIdx.x;
  uint_t w = ((const uint_t*)emb)[tid];
  uint_t e = (w >> 7) & 0xFFu;
  bool pass = (e >= 100u && e <= 127u);
  unsigned long long m = __ballot(pass);
  __shared__ int cnt[4];
  if ((tid & 63) == 0) cnt[tid >> 6] = __popcll(m);
  __syncthreads();
  if (tid == 0) {
    int c = cnt[0] + cnt[1] + cnt[2] + cnt[3];
    *flag = (c >= 128) ? 0u : 1u;
  }
}

// ---------------------------------------------------------------------------
// prep: Whh -> bf16 [768][256]; dense_W -> bf16 transpose; combined gi biases
// (bih + bhh folded for r,z gates); out bias -> fp32; zero tagged h-exchange
// buffer (tag 0 == initial h state, value 0 -- re-zeroed every replay).
// ---------------------------------------------------------------------------
__global__ __launch_bounds__(256) void prep_kernel(
    const void* eWhh, const void* dWhh, const void* denseW,
    const void* ebih, const void* ebhh, const void* dbih, const void* dbhh,
    const void* outb, const uint_t* flagp,
    ushort_t* WBe, ushort_t* WBd, ushort_t* DWT,
    float* cbe, float* cbd, float* obf, u64_t* hq) {
  uint_t f = *flagp;
  int tid = blockIdx.x * blockDim.x + threadIdx.x;
  int nth = gridDim.x * blockDim.x;
  for (int i = tid; i < G3*KK; i += nth) {
    WBe[i] = f2b(ldf(eWhh, i, f));
    WBd[i] = f2b(ldf(dWhh, i, f));
  }
  for (int i = tid; i < 512*HH; i += nth) {
    int k = i / HH, c = i % HH;
    DWT[i] = f2b(ldf(denseW, (size_t)c*512 + k, f));
  }
  for (int i = tid; i < G3; i += nth) {
    float be = ldf(ebih, i, f), bd = ldf(dbih, i, f);
    if (i < 2*HH) { be += ldf(ebhh, i, f); bd += ldf(dbhh, i, f); }
    cbe[i] = be; cbd[i] = bd;
  }
  for (int i = tid; i < OUTV; i += nth) obf[i] = ldf(outb, i, f);
  for (int i = tid; i < 2*QW_PER_BUF; i += nth) hq[i] = 0ull;  // tag0 + h=0
}

// ---------------------------------------------------------------------------
// Generic MFMA GEMM: C[m][n] = sum_k A[m][k]*B[n][k] (+bias[n]), K=256 fixed.
// tshift!=0: output rows remapped m=(b*T+t) -> t*BB+b with T=1<<tshift.
// a_f32!=0: ws A operand is fp32 (converted to bf16 during staging).
// bias (if non-null) is always fp32 (prep-produced).
// ---------------------------------------------------------------------------
#define LDT 264

__global__ __launch_bounds__(256) void gemm_kernel(
    const ushort_t* A, const int* tokens, const void* emb,
    const void* Bw, int ldb, int b_off,
    const float* bias, const uint_t* flagp,
    float* Cf, ushort_t* Cb, int ldc, int M, int tshift, int a_f32) {
  __shared__ __align__(16) ushort_t Bs[64*LDT];
  __shared__ __align__(16) ushort_t As[32*LDT];
  uint_t f = *flagp;
  int tid = threadIdx.x;
  int wave = tid >> 6, lane = tid & 63;
  int n0 = blockIdx.x * 64;
#pragma unroll
  for (int it = 0; it < 8; ++it) {
    int idx = it*256 + tid;
    int row = idx >> 5, col = (idx & 31) << 3;
    size_t e = (size_t)(n0 + row)*ldb + col + b_off;
    uint4 v;
    if (f) {
      const float4* s = (const float4*)((const float*)Bw + e);
      float4 x = s[0], y = s[1];
      v.x = (uint_t)f2b(x.x) | ((uint_t)f2b(x.y) << 16);
      v.y = (uint_t)f2b(x.z) | ((uint_t)f2b(x.w) << 16);
      v.z = (uint_t)f2b(y.x) | ((uint_t)f2b(y.y) << 16);
      v.w = (uint_t)f2b(y.z) | ((uint_t)f2b(y.w) << 16);
    } else {
      v = *(const uint4*)((const ushort_t*)Bw + e);
    }
    *(uint4*)(Bs + row*LDT + col) = v;
  }
  int arow_i = lane & 15;
  float bias_v = 0.f;
  if (bias) bias_v = bias[n0 + wave*16 + arow_i];
  int koff = (lane >> 4) << 3;
  for (int m0 = blockIdx.y*32; m0 < M; m0 += gridDim.y*32) {
    __syncthreads();   // Bs ready / previous chunk compute done
#pragma unroll
    for (int it = 0; it < 4; ++it) {
      int idx = it*256 + tid;
      int row = idx >> 5, col = (idx & 31) << 3;
      uint4 v;
      if (tokens) {
        size_t e = (size_t)tokens[m0 + row]*KK + col;
        if (f) {
          const float4* s = (const float4*)((const float*)emb + e);
          float4 x = s[0], y = s[1];
          v.x = (uint_t)f2b(x.x) | ((uint_t)f2b(x.y) << 16);
          v.y = (uint_t)f2b(x.z) | ((uint_t)f2b(x.w) << 16);
          v.z = (uint_t)f2b(y.x) | ((uint_t)f2b(y.y) << 16);
          v.w = (uint_t)f2b(y.z) | ((uint_t)f2b(y.w) << 16);
        } else {
          v = *(const uint4*)((const ushort_t*)emb + e);
        }
      } else if (a_f32) {
        const float4* s = (const float4*)((const float*)A + (size_t)(m0 + row)*KK + col);
        float4 x = s[0], y = s[1];
        v.x = (uint_t)f2b(x.x) | ((uint_t)f2b(x.y) << 16);
        v.y = (uint_t)f2b(x.z) | ((uint_t)f2b(x.w) << 16);
        v.z = (uint_t)f2b(y.x) | ((uint_t)f2b(y.y) << 16);
        v.w = (uint_t)f2b(y.z) | ((uint_t)f2b(y.w) << 16);
      } else {
        v = *(const uint4*)(A + (size_t)(m0 + row)*KK + col);  // ws bf16
      }
      *(uint4*)(As + row*LDT + col) = v;
    }
    __syncthreads();
#pragma unroll
    for (int msub = 0; msub < 2; ++msub) {
      f32x4 acc = {0.f,0.f,0.f,0.f};
      const ushort_t* ap = As + (msub*16 + arow_i)*LDT + koff;
      const ushort_t* bp = Bs + (wave*16 + arow_i)*LDT + koff;
#pragma unroll
      for (int ks = 0; ks < 8; ++ks) {
        short8 af = *(const short8*)(ap + ks*32);
        short8 bf = *(const short8*)(bp + ks*32);
        acc = __builtin_amdgcn_mfma_f32_16x16x32_bf16(af, bf, acc, 0, 0, 0);
      }
      int mbase = m0 + msub*16 + (lane >> 4)*4;
      int ncol = n0 + wave*16 + arow_i;
#pragma unroll
      for (int r = 0; r < 4; ++r) {
        float val = acc[r] + bias_v;
        int mr = mbase + r;
        int orow = tshift ? (((mr & ((1 << tshift) - 1)) << 4) + (mr >> tshift)) : mr;
        if (Cf) Cf[(size_t)orow*ldc + ncol] = val;
        else    Cb[(size_t)orow*ldc + ncol] = f2b(val);
      }
    }
  }
}

// ---------------------------------------------------------------------------
// Multi-CU MFMA GRU, round 5: tagged-word h exchange, NO grid barrier.
//
// Round-4 post-mortem: structure worked (passed, weights LDS-resident) but
// 3.57 us/step = three serial coherent-point RTTs (vmcnt-drain before
// arrive, 16-way counter RMW + spin, then h loads) + fences. This round
// collapses flag+data into ONE 64-bit atomic word: {hi: 2xbf16 h, lo: step
// tag}. Readers poll exactly the 8 qwords their wave needs until tags match
// the step -- tag and value travel atomically together, so NO barrier, NO
// fences, NO release/acquire, and the publisher never waits on its stores.
//
// Safety: (1) write-after-read -- block Y publishes tag s+2 into buf[s&1]
// only after confirming all tags s+1, which implies every block published
// h_{s+1}, which implies (data dependency) every block finished reading
// buf[s&1]. (2) per-word atomicity of naturally-aligned 8B atomic loads
// gives tag/value consistency. (3) poll is guard-BOUNDED (r3 lesson): a
// broken protocol completes with wrong answer + counters, never hangs.
// (4) part[] is parity-double-buffered: the single mid-step __syncthreads
// (between part write and part read) also orders part reuse two steps on.
// ---------------------------------------------------------------------------
#define HSBF 264            // LDS row stride (bf16 elems): <=2-way banks on b128

__device__ __forceinline__ void stage_w(const ushort_t* WB, int j0, int tid,
                                        ushort_t* wlds) {
#pragma unroll
  for (int it = 0; it < 6; ++it) {
    int idx = it*256 + tid;
    int row = idx >> 5, col = (idx & 31) << 3;   // row 0..47, col 0..255 step 8
    const ushort_t* src = WB + ((size_t)((row >> 4)*HH + j0 + (row & 15)))*KK + col;
    *(uint4*)(wlds + row*HSBF + col) = *(const uint4*)src;
  }
}

__global__ __launch_bounds__(256) void gru_kernel(
    const float* gi_e, const float* gi_d, const ushort_t* WBe, const ushort_t* WBd,
    const void* ebhh, const void* dbhh, const uint_t* flagp,
    const int* elen, const int* dlen, float* eout, float* dout, u64_t* hq) {
  uint_t f = *flagp;
  __shared__ __align__(16) ushort_t wlds[48*HSBF];        // 24.75 KB
  __shared__ __align__(16) float part[2][4][3][16][17];   // 25.5 KB parity-dbuf
  const int tid = threadIdx.x;
  const int wave = tid >> 6, lane = tid & 63;
  const int mrow = lane & 15, quad = lane >> 4;           // MFMA fragment coords
  const int j0 = blockIdx.x * JD;
  const int m = tid >> 4, n = tid & 15;                   // elementwise coords
  const int j = j0 + n;

  stage_w(WBe, j0, tid, wlds);
  const float bn_e = ldf(ebhh, 2*HH + j, f);
  const float bn_d = ldf(dbhh, 2*HH + j, f);
  const int len_e = elen[m], len_d = dlen[m];
  float hreg = 0.f;
  // prefetch gi for s=0 (rows are (t,b)-interleaved: (t*BB+m))
  float grv = gi_e[(size_t)m*G3 + j];
  float gzv = gi_e[(size_t)m*G3 + HH + j];
  float gnv = gi_e[(size_t)m*G3 + 2*HH + j];
  __syncthreads();   // weights staged

  for (int s = 0; s < TE + TD; ++s) {
    if (s == TE) {   // encoder->decoder: restage weights. All threads passed
                     // step TE-1's mid-step sync (after their last wlds MFMA
                     // reads); EW phase never touches wlds. Sync after.
      stage_w(WBd, j0, tid, wlds);
      __syncthreads();
    }
    const bool enc = s < TE;
    const int t = enc ? s : s - TE;
    // ---- poll own wave's 8 tagged qwords until tags == s -----------------
    const u64_t* hbR = hq + (size_t)(s & 1)*QW_PER_BUF + mrow*128 + wave*32 + quad*4;
    u64_t qv[8];
    const uint_t target = (uint_t)s;
    int guard = 0;
    for (;;) {
      bool ok = true;
#pragma unroll
      for (int ks = 0; ks < 2; ++ks)
#pragma unroll
        for (int i = 0; i < 4; ++i) {
          qv[ks*4 + i] = __hip_atomic_load(hbR + ks*16 + i,
                                           __ATOMIC_RELAXED, __HIP_MEMORY_SCOPE_AGENT);
          ok = ok && ((uint_t)qv[ks*4 + i] == target);
        }
      if (__all(ok) || ++guard > 30000) break;   // bounded (r3 lesson)
    }
    // ---- MFMA: 3 gate tiles, wave's K-slice = [64*wave, 64*wave+64) ------
    f32x4 ar = {0.f,0.f,0.f,0.f}, az = {0.f,0.f,0.f,0.f}, an = {0.f,0.f,0.f,0.f};
#pragma unroll
    for (int ks = 0; ks < 2; ++ks) {
      union { uint_t u[4]; short8 s8; } av;
#pragma unroll
      for (int i = 0; i < 4; ++i) av.u[i] = (uint_t)(qv[ks*4 + i] >> 32);
      const ushort_t* wp = wlds + mrow*HSBF + wave*64 + ks*32 + quad*8;
      short8 b0 = *(const short8*)(wp);
      short8 b1 = *(const short8*)(wp + 16*HSBF);
      short8 b2 = *(const short8*)(wp + 32*HSBF);
      ar = __builtin_amdgcn_mfma_f32_16x16x32_bf16(av.s8, b0, ar, 0, 0, 0);
      az = __builtin_amdgcn_mfma_f32_16x16x32_bf16(av.s8, b1, az, 0, 0, 0);
      an = __builtin_amdgcn_mfma_f32_16x16x32_bf16(av.s8, b2, an, 0, 0, 0);
    }
    // ---- partial store: C-frag row=quad*4+r (m), col=mrow (n) -------------
    const int p = s & 1;
#pragma unroll
    for (int r = 0; r < 4; ++r) {
      part[p][wave][0][quad*4 + r][mrow] = ar[r];
      part[p][wave][1][quad*4 + r][mrow] = az[r];
      part[p][wave][2][quad*4 + r][mrow] = an[r];
    }
    __syncthreads();   // the ONLY per-step block barrier
    // ---- reduce K-partials + elementwise (thread owns (m, j)) ------------
    float accr = 0.f, accz = 0.f, accn = 0.f;
#pragma unroll
    for (int w = 0; w < 4; ++w) {
      accr += part[p][w][0][m][n];
      accz += part[p][w][1][m][n];
      accn += part[p][w][2][m][n];
    }
    float rr = fsig(grv + accr);                    // bih+bhh pre-folded in gi
    float zz = fsig(gzv + accz);
    float nn = ftanh(gnv + rr*(accn + (enc ? bn_e : bn_d)));
    float hc = (1.f - zz)*nn + zz*hreg;
    bool valid = t < (enc ? len_e : len_d);
    float ov = valid ? hc : 0.f;
    hreg = valid ? hc : hreg;
    if (enc) eout[((size_t)(m*TE + t))*HH + j] = ov;
    else     dout[((size_t)(m*TD + t))*HH + j] = ov;
    // ---- publish tagged h qword (even n lanes), fire-and-forget ----------
    uint_t h16 = (uint_t)f2b(hreg);
    uint_t up = (uint_t)__shfl_down((int)h16, 1);
    if (!(n & 1)) {
      u64_t q = ((u64_t)(h16 | (up << 16)) << 32) | (u64_t)(uint_t)(s + 1);
      __hip_atomic_store(hq + (size_t)((s + 1) & 1)*QW_PER_BUF + m*128 + (j >> 1),
                         q, __ATOMIC_RELAXED, __HIP_MEMORY_SCOPE_AGENT);
    }
    // ---- prefetch next step's gi (overlaps next poll) --------------------
    int s2 = s + 1;
    if (s2 < TE + TD) {
      const float* g2 = (s2 < TE) ? (gi_e + (size_t)(s2*BB + m)*G3)
                                  : (gi_d + (size_t)((s2 - TE)*BB + m)*G3);
      grv = g2[j]; gzv = g2[HH + j]; gnv = g2[2*HH + j];
    }
  }
}

// ---------------------------------------------------------------------------
// Attention + dense, one block per (b, td). (unchanged)
// ---------------------------------------------------------------------------
__global__ __launch_bounds__(256) void attn_kernel(
    const float* eprj, const float* dprj, const float* eout, const float* dout,
    const void* Wb, const void* av, const void* avb,
    const ushort_t* DWT, const void* db, const uint_t* flagp,
    const int* elen, const int* dlen, ushort_t* dense_bf) {
  int bd = blockIdx.x;
  int b = bd / TD, td = bd % TD;
  int tid = threadIdx.x;
  int wave = tid >> 6, lane = tid & 63;
  uint_t f = *flagp;
  __shared__ float dp[HH], dsrow[HH], vv[HH], att[TE];
  int el = elen[b];
  bool dok = td < dlen[b];
  size_t drow = (size_t)bd * HH;
  dp[tid] = dprj[drow + tid] + ldf(Wb, tid, f);
  dsrow[tid] = dout[drow + tid];
  vv[tid] = ldf(av, tid, f);
  __syncthreads();
  float vb0 = ldf(avb, 0, f);
  for (int teb = 0; teb < TE/4; ++teb) {
    int te = teb*4 + wave;
    float e = -1e30f;
    if (dok && te < el) {
      const float* ep = eprj + (size_t)(b*TE + te)*HH;
      float s = 0.f;
#pragma unroll
      for (int i = 0; i < 4; ++i) {
        int hh = lane + 64*i;
        s += tanhf(ep[hh] + dp[hh]) * vv[hh];
      }
#pragma unroll
      for (int off = 32; off > 0; off >>= 1) s += __shfl_xor(s, off);
      e = s + vb0;
    }
    if (lane == 0) att[te] = e;
  }
  __syncthreads();
  float m = -1e30f;
  for (int te = 0; te < TE; ++te) m = fmaxf(m, att[te]);
  __syncthreads();
  if (tid < TE) {
    float e = att[tid];
    att[tid] = (e > -1e29f) ? expf(e - m) : 0.f;
  }
  __syncthreads();
  float ssum = 0.f;
  for (int te = 0; te < TE; ++te) ssum += att[te];
  float inv = (ssum > 0.f) ? 1.f/ssum : 0.f;
  float c = 0.f;
  for (int te = 0; te < TE; ++te) {
    float wgt = att[te];
    if (wgt > 0.f) c += wgt * eout[(size_t)(b*TE + te)*HH + tid];
  }
  c *= inv;
  __syncthreads();
  dp[tid] = c;   // reuse dp as context
  __syncthreads();
  float acc = ldf(db, tid, f);
#pragma unroll 4
  for (int k = 0; k < HH; ++k) acc = fmaf(b2f(DWT[k*HH + tid]), dsrow[k], acc);
#pragma unroll 4
  for (int k = 0; k < HH; ++k) acc = fmaf(b2f(DWT[(HH + k)*HH + tid]), dp[k], acc);
  dense_bf[drow + tid] = f2b(tanhf(acc));
}

// ---------------------------------------------------------------------------
extern "C" void kernel_launch(void* const* d_in, const int* in_sizes, int n_in,
                              void* d_out, int out_size, void* d_ws, size_t ws_size,
                              hipStream_t stream) {
  const int* enc_in   = (const int*)d_in[0];
  const int* enc_len  = (const int*)d_in[1];
  const int* dec_in   = (const int*)d_in[2];
  const int* dec_len  = (const int*)d_in[3];
  const void* emb    = d_in[4];
  const void* eWih   = d_in[5];
  const void* eWhh   = d_in[6];
  const void* ebih   = d_in[7];
  const void* ebhh   = d_in[8];
  const void* dWih   = d_in[9];
  const void* dWhh   = d_in[10];
  const void* dbih   = d_in[11];
  const void* dbhh   = d_in[12];
  const void* attnW  = d_in[13];
  const void* attnWb = d_in[14];
  const void* attnv  = d_in[15];
  const void* attnvb = d_in[16];
  const void* denseW = d_in[17];
  const void* denseb = d_in[18];
  const void* outW   = d_in[19];
  const void* outb   = d_in[20];
  float* out = (float*)d_out;   // reference output is fp32

  float* ws = (float*)d_ws;
  size_t o = 0;
  uint_t* flag = (uint_t*)(ws + o);   o += 4;
  u64_t* hq = (u64_t*)(ws + o);       o += 4*QW_PER_BUF;  // 2 bufs x 2048 qwords
  ushort_t* WBe = (ushort_t*)(ws + o); o += G3*KK/2;
  ushort_t* WBd = (ushort_t*)(ws + o); o += G3*KK/2;
  ushort_t* DWT = (ushort_t*)(ws + o); o += 512*HH/2;
  float* cbe = ws + o;                o += G3;
  float* cbd = ws + o;                o += G3;
  float* obf = ws + o;                o += OUTV;
  float* gi_e = ws + o;               o += (size_t)MROWS_E*G3;   // (t,b)-interleaved
  float* gi_d = ws + o;               o += (size_t)MROWS_D*G3;   // (t,b)-interleaved
  float* eout = ws + o;               o += (size_t)MROWS_E*HH;
  float* dout = ws + o;               o += (size_t)MROWS_D*HH;
  float* eprj = ws + o;               o += (size_t)MROWS_E*HH;
  float* dprj = ws + o;               o += (size_t)MROWS_D*HH;
  ushort_t* dense_bf = (ushort_t*)(ws + o); o += (size_t)MROWS_D*HH/2;

  detect_kernel<<<1, 256, 0, stream>>>(emb, flag);
  prep_kernel<<<384, 256, 0, stream>>>(eWhh, dWhh, denseW, ebih, ebhh, dbih, dbhh,
                                       outb, flag, WBe, WBd, DWT, cbe, cbd, obf, hq);
  // gi = emb[tokens] @ Wih.T + (bih + bhh[r,z]), rows (t,b)-interleaved
  gemm_kernel<<<dim3(12,8), 256, 0, stream>>>(nullptr, enc_in, emb, eWih, 256, 0,
                                              cbe, flag, gi_e, nullptr, G3, MROWS_E, 7, 0);
  gemm_kernel<<<dim3(12,4), 256, 0, stream>>>(nullptr, dec_in, emb, dWih, 256, 0,
                                              cbd, flag, gi_d, nullptr, G3, MROWS_D, 6, 0);
  gru_kernel<<<NBLK, 256, 0, stream>>>(gi_e, gi_d, WBe, WBd, ebhh, dbhh, flag,
                                       enc_len, dec_len, eout, dout, hq);
  // enc_proj = enc_out @ W1.T ; dec_proj = dec_out @ W2.T  (attn_W col split)
  gemm_kernel<<<dim3(4,16), 256, 0, stream>>>((const ushort_t*)eout, nullptr, nullptr,
                                              attnW, 512, 0, nullptr, flag, eprj,
                                              nullptr, HH, MROWS_E, 0, 1);
  gemm_kernel<<<dim3(4,8), 256, 0, stream>>>((const ushort_t*)dout, nullptr, nullptr,
                                             attnW, 512, 256, nullptr, flag, dprj,
                                             nullptr, HH, MROWS_D, 0, 1);
  attn_kernel<<<MROWS_D, 256, 0, stream>>>(eprj, dprj, eout, dout, attnWb, attnv, attnvb,
                                           DWT, denseb, flag, enc_len, dec_len, dense_bf);
  // logits = dense @ out_W.T + out_b  (fp32 out)
  gemm_kernel<<<dim3(500,4), 256, 0, stream>>>(dense_bf, nullptr, nullptr, outW, 256, 0,
                                               obf, flag, out, nullptr, OUTV, MROWS_D, 0, 0);
}

// Round 6
// 826.659 us; speedup vs baseline: 1.8980x; 1.1545x over previous
//
#include <hip/hip_runtime.h>
#include <hip/hip_bf16.h>

typedef unsigned short ushort_t;
typedef unsigned int uint_t;
typedef unsigned long long u64_t;

#define BB 16
#define TE 128
#define TD 64
#define HH 256
#define G3 768
#define KK 256
#define OUTV 32000
#define MROWS_E (BB*TE)   // 2048
#define MROWS_D (BB*TD)   // 1024
#define NBLK 16           // GRU blocks (CUs); each owns JD h-dims
#define JD 16
#define QW_PER_BUF 2048   // {2xbf16, tag} qwords per h snapshot

typedef __attribute__((ext_vector_type(8))) short short8;
typedef __attribute__((ext_vector_type(4))) float f32x4;

__device__ __forceinline__ float b2f(ushort_t u) {
  union { uint_t i; float f; } v; v.i = ((uint_t)u) << 16; return v.f;
}
__device__ __forceinline__ ushort_t f2b(float f) {
  union { float f; uint_t i; } v; v.f = f;
  uint_t x = v.i;
  return (ushort_t)((x + 0x7fffu + ((x >> 16) & 1u)) >> 16);
}
// dtype-adaptive scalar load of a "float" input: f32f!=0 -> fp32 buffer, else bf16
__device__ __forceinline__ float ldf(const void* p, size_t i, uint_t f32f) {
  return f32f ? ((const float*)p)[i] : b2f(((const ushort_t*)p)[i]);
}
// fast, saturating sigmoid/tanh (inputs bounded; formulas robust at +-inf)
__device__ __forceinline__ float fsig(float x) { return 1.f/(1.f + __expf(-x)); }
__device__ __forceinline__ float ftanh(float x) { return 1.f - 2.f/(__expf(2.f*x) + 1.f); }

// ---------------------------------------------------------------------------
// dtype detector (fp32 on this harness; kept for safety).
// ---------------------------------------------------------------------------
__global__ __launch_bounds__(256) void detect_kernel(const void* emb, uint_t* flag) {
  int tid = threadIdx.x;
  uint_t w = ((const uint_t*)emb)[tid];
  uint_t e = (w >> 7) & 0xFFu;
  bool pass = (e >= 100u && e <= 127u);
  unsigned long long m = __ballot(pass);
  __shared__ int cnt[4];
  if ((tid & 63) == 0) cnt[tid >> 6] = __popcll(m);
  __syncthreads();
  if (tid == 0) {
    int c = cnt[0] + cnt[1] + cnt[2] + cnt[3];
    *flag = (c >= 128) ? 0u : 1u;
  }
}

// ---------------------------------------------------------------------------
// prep: Whh -> bf16 [768][256]; dense_W -> bf16 transpose; combined gi biases
// (bih + bhh folded for r,z gates); out bias -> fp32; zero tagged h-exchange
// buffer (tag 0 == initial h state, value 0 -- re-zeroed every replay).
// ---------------------------------------------------------------------------
__global__ __launch_bounds__(256) void prep_kernel(
    const void* eWhh, const void* dWhh, const void* denseW,
    const void* ebih, const void* ebhh, const void* dbih, const void* dbhh,
    const void* outb, const uint_t* flagp,
    ushort_t* WBe, ushort_t* WBd, ushort_t* DWT,
    float* cbe, float* cbd, float* obf, u64_t* hq) {
  uint_t f = *flagp;
  int tid = blockIdx.x * blockDim.x + threadIdx.x;
  int nth = gridDim.x * blockDim.x;
  for (int i = tid; i < G3*KK; i += nth) {
    WBe[i] = f2b(ldf(eWhh, i, f));
    WBd[i] = f2b(ldf(dWhh, i, f));
  }
  for (int i = tid; i < 512*HH; i += nth) {
    int k = i / HH, c = i % HH;
    DWT[i] = f2b(ldf(denseW, (size_t)c*512 + k, f));
  }
  for (int i = tid; i < G3; i += nth) {
    float be = ldf(ebih, i, f), bd = ldf(dbih, i, f);
    if (i < 2*HH) { be += ldf(ebhh, i, f); bd += ldf(dbhh, i, f); }
    cbe[i] = be; cbd[i] = bd;
  }
  for (int i = tid; i < OUTV; i += nth) obf[i] = ldf(outb, i, f);
  for (int i = tid; i < 2*QW_PER_BUF; i += nth) hq[i] = 0ull;  // tag0 + h=0
}

// ---------------------------------------------------------------------------
// Generic MFMA GEMM: C[m][n] = sum_k A[m][k]*B[n][k] (+bias[n]), K=256 fixed.
// tshift!=0: output rows remapped m=(b*T+t) -> t*BB+b with T=1<<tshift.
// a_f32!=0: ws A operand is fp32 (converted to bf16 during staging).
// bias (if non-null) is always fp32 (prep-produced).
// ---------------------------------------------------------------------------
#define LDT 264

__global__ __launch_bounds__(256) void gemm_kernel(
    const ushort_t* A, const int* tokens, const void* emb,
    const void* Bw, int ldb, int b_off,
    const float* bias, const uint_t* flagp,
    float* Cf, ushort_t* Cb, int ldc, int M, int tshift, int a_f32) {
  __shared__ __align__(16) ushort_t Bs[64*LDT];
  __shared__ __align__(16) ushort_t As[32*LDT];
  uint_t f = *flagp;
  int tid = threadIdx.x;
  int wave = tid >> 6, lane = tid & 63;
  int n0 = blockIdx.x * 64;
#pragma unroll
  for (int it = 0; it < 8; ++it) {
    int idx = it*256 + tid;
    int row = idx >> 5, col = (idx & 31) << 3;
    size_t e = (size_t)(n0 + row)*ldb + col + b_off;
    uint4 v;
    if (f) {
      const float4* s = (const float4*)((const float*)Bw + e);
      float4 x = s[0], y = s[1];
      v.x = (uint_t)f2b(x.x) | ((uint_t)f2b(x.y) << 16);
      v.y = (uint_t)f2b(x.z) | ((uint_t)f2b(x.w) << 16);
      v.z = (uint_t)f2b(y.x) | ((uint_t)f2b(y.y) << 16);
      v.w = (uint_t)f2b(y.z) | ((uint_t)f2b(y.w) << 16);
    } else {
      v = *(const uint4*)((const ushort_t*)Bw + e);
    }
    *(uint4*)(Bs + row*LDT + col) = v;
  }
  int arow_i = lane & 15;
  float bias_v = 0.f;
  if (bias) bias_v = bias[n0 + wave*16 + arow_i];
  int koff = (lane >> 4) << 3;
  for (int m0 = blockIdx.y*32; m0 < M; m0 += gridDim.y*32) {
    __syncthreads();   // Bs ready / previous chunk compute done
#pragma unroll
    for (int it = 0; it < 4; ++it) {
      int idx = it*256 + tid;
      int row = idx >> 5, col = (idx & 31) << 3;
      uint4 v;
      if (tokens) {
        size_t e = (size_t)tokens[m0 + row]*KK + col;
        if (f) {
          const float4* s = (const float4*)((const float*)emb + e);
          float4 x = s[0], y = s[1];
          v.x = (uint_t)f2b(x.x) | ((uint_t)f2b(x.y) << 16);
          v.y = (uint_t)f2b(x.z) | ((uint_t)f2b(x.w) << 16);
          v.z = (uint_t)f2b(y.x) | ((uint_t)f2b(y.y) << 16);
          v.w = (uint_t)f2b(y.z) | ((uint_t)f2b(y.w) << 16);
        } else {
          v = *(const uint4*)((const ushort_t*)emb + e);
        }
      } else if (a_f32) {
        const float4* s = (const float4*)((const float*)A + (size_t)(m0 + row)*KK + col);
        float4 x = s[0], y = s[1];
        v.x = (uint_t)f2b(x.x) | ((uint_t)f2b(x.y) << 16);
        v.y = (uint_t)f2b(x.z) | ((uint_t)f2b(x.w) << 16);
        v.z = (uint_t)f2b(y.x) | ((uint_t)f2b(y.y) << 16);
        v.w = (uint_t)f2b(y.z) | ((uint_t)f2b(y.w) << 16);
      } else {
        v = *(const uint4*)(A + (size_t)(m0 + row)*KK + col);  // ws bf16
      }
      *(uint4*)(As + row*LDT + col) = v;
    }
    __syncthreads();
#pragma unroll
    for (int msub = 0; msub < 2; ++msub) {
      f32x4 acc = {0.f,0.f,0.f,0.f};
      const ushort_t* ap = As + (msub*16 + arow_i)*LDT + koff;
      const ushort_t* bp = Bs + (wave*16 + arow_i)*LDT + koff;
#pragma unroll
      for (int ks = 0; ks < 8; ++ks) {
        short8 af = *(const short8*)(ap + ks*32);
        short8 bf = *(const short8*)(bp + ks*32);
        acc = __builtin_amdgcn_mfma_f32_16x16x32_bf16(af, bf, acc, 0, 0, 0);
      }
      int mbase = m0 + msub*16 + (lane >> 4)*4;
      int ncol = n0 + wave*16 + arow_i;
#pragma unroll
      for (int r = 0; r < 4; ++r) {
        float val = acc[r] + bias_v;
        int mr = mbase + r;
        int orow = tshift ? (((mr & ((1 << tshift) - 1)) << 4) + (mr >> tshift)) : mr;
        if (Cf) Cf[(size_t)orow*ldc + ncol] = val;
        else    Cb[(size_t)orow*ldc + ncol] = f2b(val);
      }
    }
  }
}

// ---------------------------------------------------------------------------
// Multi-CU MFMA GRU, round 6: tagged-word h exchange with a COALESCED layout.
//
// Round-5 post-mortem: tagged words removed the barrier (686->457 us) but
// the poll read pattern put consecutive lanes 1 KB apart (mrow*128 qwords):
// every poll load was a 64-line scatter -> 512 IF$ transactions per wave
// per iteration, x4 waves x16 blocks, re-issued until tags flip. The step
// time was coherent-point QUEUING, not RTT.
//
// Fix: each {2xbf16, tag} qword is consumed by exactly one (wave,ks,i,lane)
// tuple, identically in all 16 reader blocks, so the layout is free. Qword
// index = wave*512 + ks*256 + i*64 + (quad*16 + mrow) = ... + lane: each of
// the 8 poll loads is 64 CONSECUTIVE qwords per wave (8 lines, fully
// coalesced) -- 64x fewer transactions. Publisher computes the permuted
// index from j (bit shuffle); its stores coalesce in 16-qword runs.
// Protocol (tags, double buffer, bounded guard, single per-step sync) is
// unchanged from round 5.
// ---------------------------------------------------------------------------
#define HSBF 264            // LDS row stride (bf16 elems): <=2-way banks on b128

__device__ __forceinline__ void stage_w(const ushort_t* WB, int j0, int tid,
                                        ushort_t* wlds) {
#pragma unroll
  for (int it = 0; it < 6; ++it) {
    int idx = it*256 + tid;
    int row = idx >> 5, col = (idx & 31) << 3;   // row 0..47, col 0..255 step 8
    const ushort_t* src = WB + ((size_t)((row >> 4)*HH + j0 + (row & 15)))*KK + col;
    *(uint4*)(wlds + row*HSBF + col) = *(const uint4*)src;
  }
}

__global__ __launch_bounds__(256) void gru_kernel(
    const float* gi_e, const float* gi_d, const ushort_t* WBe, const ushort_t* WBd,
    const void* ebhh, const void* dbhh, const uint_t* flagp,
    const int* elen, const int* dlen, float* eout, float* dout, u64_t* hq) {
  uint_t f = *flagp;
  __shared__ __align__(16) ushort_t wlds[48*HSBF];        // 24.75 KB
  __shared__ __align__(16) float part[2][4][3][16][17];   // 25.5 KB parity-dbuf
  const int tid = threadIdx.x;
  const int wave = tid >> 6, lane = tid & 63;
  const int mrow = lane & 15, quad = lane >> 4;           // MFMA fragment coords
  const int j0 = blockIdx.x * JD;
  const int m = tid >> 4, n = tid & 15;                   // elementwise coords
  const int j = j0 + n;
  // permuted publish index for this thread's (even) pair base j & ~1:
  const int je = j & ~1;
  const int widx = ((je >> 6) << 9) + (((je >> 5) & 1) << 8)
                 + (((je >> 1) & 3) << 6) + (((je >> 3) & 3) << 4) + m;

  stage_w(WBe, j0, tid, wlds);
  const float bn_e = ldf(ebhh, 2*HH + j, f);
  const float bn_d = ldf(dbhh, 2*HH + j, f);
  const int len_e = elen[m], len_d = dlen[m];
  float hreg = 0.f;
  // prefetch gi for s=0 (rows are (t,b)-interleaved: (t*BB+m))
  float grv = gi_e[(size_t)m*G3 + j];
  float gzv = gi_e[(size_t)m*G3 + HH + j];
  float gnv = gi_e[(size_t)m*G3 + 2*HH + j];
  __syncthreads();   // weights staged

  for (int s = 0; s < TE + TD; ++s) {
    if (s == TE) {   // encoder->decoder: restage weights. All threads passed
                     // step TE-1's mid-step sync (after their last wlds MFMA
                     // reads); EW phase never touches wlds. Sync after.
      stage_w(WBd, j0, tid, wlds);
      __syncthreads();
    }
    const bool enc = s < TE;
    const int t = enc ? s : s - TE;
    // ---- poll own wave's 8 tagged qwords (coalesced layout) --------------
    const u64_t* hbR = hq + (size_t)(s & 1)*QW_PER_BUF + wave*512 + lane;
    u64_t qv[8];
    const uint_t target = (uint_t)s;
    int guard = 0;
    for (;;) {
      bool ok = true;
#pragma unroll
      for (int ks = 0; ks < 2; ++ks)
#pragma unroll
        for (int i = 0; i < 4; ++i) {
          qv[ks*4 + i] = __hip_atomic_load(hbR + ks*256 + i*64,
                                           __ATOMIC_RELAXED, __HIP_MEMORY_SCOPE_AGENT);
          ok = ok && ((uint_t)qv[ks*4 + i] == target);
        }
      if (__all(ok) || ++guard > 30000) break;   // bounded (r3 lesson)
    }
    // ---- MFMA: 3 gate tiles, wave's K-slice = [64*wave, 64*wave+64) ------
    f32x4 ar = {0.f,0.f,0.f,0.f}, az = {0.f,0.f,0.f,0.f}, an = {0.f,0.f,0.f,0.f};
#pragma unroll
    for (int ks = 0; ks < 2; ++ks) {
      union { uint_t u[4]; short8 s8; } av;
#pragma unroll
      for (int i = 0; i < 4; ++i) av.u[i] = (uint_t)(qv[ks*4 + i] >> 32);
      const ushort_t* wp = wlds + mrow*HSBF + wave*64 + ks*32 + quad*8;
      short8 b0 = *(const short8*)(wp);
      short8 b1 = *(const short8*)(wp + 16*HSBF);
      short8 b2 = *(const short8*)(wp + 32*HSBF);
      ar = __builtin_amdgcn_mfma_f32_16x16x32_bf16(av.s8, b0, ar, 0, 0, 0);
      az = __builtin_amdgcn_mfma_f32_16x16x32_bf16(av.s8, b1, az, 0, 0, 0);
      an = __builtin_amdgcn_mfma_f32_16x16x32_bf16(av.s8, b2, an, 0, 0, 0);
    }
    // ---- partial store: C-frag row=quad*4+r (m), col=mrow (n) -------------
    const int p = s & 1;
#pragma unroll
    for (int r = 0; r < 4; ++r) {
      part[p][wave][0][quad*4 + r][mrow] = ar[r];
      part[p][wave][1][quad*4 + r][mrow] = az[r];
      part[p][wave][2][quad*4 + r][mrow] = an[r];
    }
    __syncthreads();   // the ONLY per-step block barrier
    // ---- reduce K-partials + elementwise (thread owns (m, j)) ------------
    float accr = 0.f, accz = 0.f, accn = 0.f;
#pragma unroll
    for (int w = 0; w < 4; ++w) {
      accr += part[p][w][0][m][n];
      accz += part[p][w][1][m][n];
      accn += part[p][w][2][m][n];
    }
    float rr = fsig(grv + accr);                    // bih+bhh pre-folded in gi
    float zz = fsig(gzv + accz);
    float nn = ftanh(gnv + rr*(accn + (enc ? bn_e : bn_d)));
    float hc = (1.f - zz)*nn + zz*hreg;
    bool valid = t < (enc ? len_e : len_d);
    float ov = valid ? hc : 0.f;
    hreg = valid ? hc : hreg;
    if (enc) eout[((size_t)(m*TE + t))*HH + j] = ov;
    else     dout[((size_t)(m*TD + t))*HH + j] = ov;
    // ---- publish tagged h qword (even n lanes), fire-and-forget ----------
    uint_t h16 = (uint_t)f2b(hreg);
    uint_t up = (uint_t)__shfl_down((int)h16, 1);
    if (!(n & 1)) {
      u64_t q = ((u64_t)(h16 | (up << 16)) << 32) | (u64_t)(uint_t)(s + 1);
      __hip_atomic_store(hq + (size_t)((s + 1) & 1)*QW_PER_BUF + widx,
                         q, __ATOMIC_RELAXED, __HIP_MEMORY_SCOPE_AGENT);
    }
    // ---- prefetch next step's gi (overlaps next poll) --------------------
    int s2 = s + 1;
    if (s2 < TE + TD) {
      const float* g2 = (s2 < TE) ? (gi_e + (size_t)(s2*BB + m)*G3)
                                  : (gi_d + (size_t)((s2 - TE)*BB + m)*G3);
      grv = g2[j]; gzv = g2[HH + j]; gnv = g2[2*HH + j];
    }
  }
}

// ---------------------------------------------------------------------------
// Attention + dense, one block per (b, td). (unchanged)
// ---------------------------------------------------------------------------
__global__ __launch_bounds__(256) void attn_kernel(
    const float* eprj, const float* dprj, const float* eout, const float* dout,
    const void* Wb, const void* av, const void* avb,
    const ushort_t* DWT, const void* db, const uint_t* flagp,
    const int* elen, const int* dlen, ushort_t* dense_bf) {
  int bd = blockIdx.x;
  int b = bd / TD, td = bd % TD;
  int tid = threadIdx.x;
  int wave = tid >> 6, lane = tid & 63;
  uint_t f = *flagp;
  __shared__ float dp[HH], dsrow[HH], vv[HH], att[TE];
  int el = elen[b];
  bool dok = td < dlen[b];
  size_t drow = (size_t)bd * HH;
  dp[tid] = dprj[drow + tid] + ldf(Wb, tid, f);
  dsrow[tid] = dout[drow + tid];
  vv[tid] = ldf(av, tid, f);
  __syncthreads();
  float vb0 = ldf(avb, 0, f);
  for (int teb = 0; teb < TE/4; ++teb) {
    int te = teb*4 + wave;
    float e = -1e30f;
    if (dok && te < el) {
      const float* ep = eprj + (size_t)(b*TE + te)*HH;
      float s = 0.f;
#pragma unroll
      for (int i = 0; i < 4; ++i) {
        int hh = lane + 64*i;
        s += tanhf(ep[hh] + dp[hh]) * vv[hh];
      }
#pragma unroll
      for (int off = 32; off > 0; off >>= 1) s += __shfl_xor(s, off);
      e = s + vb0;
    }
    if (lane == 0) att[te] = e;
  }
  __syncthreads();
  float m = -1e30f;
  for (int te = 0; te < TE; ++te) m = fmaxf(m, att[te]);
  __syncthreads();
  if (tid < TE) {
    float e = att[tid];
    att[tid] = (e > -1e29f) ? expf(e - m) : 0.f;
  }
  __syncthreads();
  float ssum = 0.f;
  for (int te = 0; te < TE; ++te) ssum += att[te];
  float inv = (ssum > 0.f) ? 1.f/ssum : 0.f;
  float c = 0.f;
  for (int te = 0; te < TE; ++te) {
    float wgt = att[te];
    if (wgt > 0.f) c += wgt * eout[(size_t)(b*TE + te)*HH + tid];
  }
  c *= inv;
  __syncthreads();
  dp[tid] = c;   // reuse dp as context
  __syncthreads();
  float acc = ldf(db, tid, f);
#pragma unroll 4
  for (int k = 0; k < HH; ++k) acc = fmaf(b2f(DWT[k*HH + tid]), dsrow[k], acc);
#pragma unroll 4
  for (int k = 0; k < HH; ++k) acc = fmaf(b2f(DWT[(HH + k)*HH + tid]), dp[k], acc);
  dense_bf[drow + tid] = f2b(tanhf(acc));
}

// ---------------------------------------------------------------------------
extern "C" void kernel_launch(void* const* d_in, const int* in_sizes, int n_in,
                              void* d_out, int out_size, void* d_ws, size_t ws_size,
                              hipStream_t stream) {
  const int* enc_in   = (const int*)d_in[0];
  const int* enc_len  = (const int*)d_in[1];
  const int* dec_in   = (const int*)d_in[2];
  const int* dec_len  = (const int*)d_in[3];
  const void* emb    = d_in[4];
  const void* eWih   = d_in[5];
  const void* eWhh   = d_in[6];
  const void* ebih   = d_in[7];
  const void* ebhh   = d_in[8];
  const void* dWih   = d_in[9];
  const void* dWhh   = d_in[10];
  const void* dbih   = d_in[11];
  const void* dbhh   = d_in[12];
  const void* attnW  = d_in[13];
  const void* attnWb = d_in[14];
  const void* attnv  = d_in[15];
  const void* attnvb = d_in[16];
  const void* denseW = d_in[17];
  const void* denseb = d_in[18];
  const void* outW   = d_in[19];
  const void* outb   = d_in[20];
  float* out = (float*)d_out;   // reference output is fp32

  float* ws = (float*)d_ws;
  size_t o = 0;
  uint_t* flag = (uint_t*)(ws + o);   o += 4;
  u64_t* hq = (u64_t*)(ws + o);       o += 4*QW_PER_BUF;  // 2 bufs x 2048 qwords
  ushort_t* WBe = (ushort_t*)(ws + o); o += G3*KK/2;
  ushort_t* WBd = (ushort_t*)(ws + o); o += G3*KK/2;
  ushort_t* DWT = (ushort_t*)(ws + o); o += 512*HH/2;
  float* cbe = ws + o;                o += G3;
  float* cbd = ws + o;                o += G3;
  float* obf = ws + o;                o += OUTV;
  float* gi_e = ws + o;               o += (size_t)MROWS_E*G3;   // (t,b)-interleaved
  float* gi_d = ws + o;               o += (size_t)MROWS_D*G3;   // (t,b)-interleaved
  float* eout = ws + o;               o += (size_t)MROWS_E*HH;
  float* dout = ws + o;               o += (size_t)MROWS_D*HH;
  float* eprj = ws + o;               o += (size_t)MROWS_E*HH;
  float* dprj = ws + o;               o += (size_t)MROWS_D*HH;
  ushort_t* dense_bf = (ushort_t*)(ws + o); o += (size_t)MROWS_D*HH/2;

  detect_kernel<<<1, 256, 0, stream>>>(emb, flag);
  prep_kernel<<<384, 256, 0, stream>>>(eWhh, dWhh, denseW, ebih, ebhh, dbih, dbhh,
                                       outb, flag, WBe, WBd, DWT, cbe, cbd, obf, hq);
  // gi = emb[tokens] @ Wih.T + (bih + bhh[r,z]), rows (t,b)-interleaved
  gemm_kernel<<<dim3(12,8), 256, 0, stream>>>(nullptr, enc_in, emb, eWih, 256, 0,
                                              cbe, flag, gi_e, nullptr, G3, MROWS_E, 7, 0);
  gemm_kernel<<<dim3(12,4), 256, 0, stream>>>(nullptr, dec_in, emb, dWih, 256, 0,
                                              cbd, flag, gi_d, nullptr, G3, MROWS_D, 6, 0);
  gru_kernel<<<NBLK, 256, 0, stream>>>(gi_e, gi_d, WBe, WBd, ebhh, dbhh, flag,
                                       enc_len, dec_len, eout, dout, hq);
  // enc_proj = enc_out @ W1.T ; dec_proj = dec_out @ W2.T  (attn_W col split)
  gemm_kernel<<<dim3(4,16), 256, 0, stream>>>((const ushort_t*)eout, nullptr, nullptr,
                                              attnW, 512, 0, nullptr, flag, eprj,
                                              nullptr, HH, MROWS_E, 0, 1);
  gemm_kernel<<<dim3(4,8), 256, 0, stream>>>((const ushort_t*)dout, nullptr, nullptr,
                                             attnW, 512, 256, nullptr, flag, dprj,
                                             nullptr, HH, MROWS_D, 0, 1);
  attn_kernel<<<MROWS_D, 256, 0, stream>>>(eprj, dprj, eout, dout, attnWb, attnv, attnvb,
                                           DWT, denseb, flag, enc_len, dec_len, dense_bf);
  // logits = dense @ out_W.T + out_b  (fp32 out)
  gemm_kernel<<<dim3(500,4), 256, 0, stream>>>(dense_bf, nullptr, nullptr, outW, 256, 0,
                                               obf, flag, out, nullptr, OUTV, MROWS_D, 0, 0);
}

// Round 8
// 743.625 us; speedup vs baseline: 2.1099x; 1.1117x over previous
//
#include <hip/hip_runtime.h>
#include <hip/hip_bf16.h>

typedef unsigned short ushort_t;
typedef unsigned int uint_t;
typedef unsigned long long u64_t;

#define BB 16
#define TE 128
#define TD 64
#define HH 256
#define G3 768
#define KK 256
#define OUTV 32000
#define MROWS_E (BB*TE)   // 2048
#define MROWS_D (BB*TD)   // 1024
#define NBLK 16           // GRU blocks (CUs); each owns JD h-dims
#define JD 16
#define QW_PER_BUF 2048   // {2xbf16, tag} qwords per h snapshot

typedef __attribute__((ext_vector_type(8))) short short8;
typedef __attribute__((ext_vector_type(4))) float f32x4;

__device__ __forceinline__ float b2f(ushort_t u) {
  union { uint_t i; float f; } v; v.i = ((uint_t)u) << 16; return v.f;
}
__device__ __forceinline__ ushort_t f2b(float f) {
  union { float f; uint_t i; } v; v.f = f;
  uint_t x = v.i;
  return (ushort_t)((x + 0x7fffu + ((x >> 16) & 1u)) >> 16);
}
// dtype-adaptive scalar load of a "float" input: f32f!=0 -> fp32 buffer, else bf16
__device__ __forceinline__ float ldf(const void* p, size_t i, uint_t f32f) {
  return f32f ? ((const float*)p)[i] : b2f(((const ushort_t*)p)[i]);
}
// fast, saturating sigmoid/tanh (inputs bounded; formulas robust at +-inf)
__device__ __forceinline__ float fsig(float x) { return 1.f/(1.f + __expf(-x)); }
__device__ __forceinline__ float ftanh(float x) { return 1.f - 2.f/(__expf(2.f*x) + 1.f); }

// ---------------------------------------------------------------------------
// dtype detector (fp32 on this harness; kept for safety).
// ---------------------------------------------------------------------------
__global__ __launch_bounds__(256) void detect_kernel(const void* emb, uint_t* flag) {
  int tid = threadIdx.x;
  uint_t w = ((const uint_t*)emb)[tid];
  uint_t e = (w >> 7) & 0xFFu;
  bool pass = (e >= 100u && e <= 127u);
  unsigned long long m = __ballot(pass);
  __shared__ int cnt[4];
  if ((tid & 63) == 0) cnt[tid >> 6] = __popcll(m);
  __syncthreads();
  if (tid == 0) {
    int c = cnt[0] + cnt[1] + cnt[2] + cnt[3];
    *flag = (c >= 128) ? 0u : 1u;
  }
}

// ---------------------------------------------------------------------------
// prep: Whh -> bf16 [768][256]; dense_W -> bf16 transpose; combined gi biases
// (bih + bhh folded for r,z gates); out bias -> fp32; zero tagged h-exchange
// buffer (tag 0 == initial h state, value 0 -- re-zeroed every replay).
// ---------------------------------------------------------------------------
__global__ __launch_bounds__(256) void prep_kernel(
    const void* eWhh, const void* dWhh, const void* denseW,
    const void* ebih, const void* ebhh, const void* dbih, const void* dbhh,
    const void* outb, const uint_t* flagp,
    ushort_t* WBe, ushort_t* WBd, ushort_t* DWT,
    float* cbe, float* cbd, float* obf, u64_t* hq) {
  uint_t f = *flagp;
  int tid = blockIdx.x * blockDim.x + threadIdx.x;
  int nth = gridDim.x * blockDim.x;
  for (int i = tid; i < G3*KK; i += nth) {
    WBe[i] = f2b(ldf(eWhh, i, f));
    WBd[i] = f2b(ldf(dWhh, i, f));
  }
  for (int i = tid; i < 512*HH; i += nth) {
    int k = i / HH, c = i % HH;
    DWT[i] = f2b(ldf(denseW, (size_t)c*512 + k, f));
  }
  for (int i = tid; i < G3; i += nth) {
    float be = ldf(ebih, i, f), bd = ldf(dbih, i, f);
    if (i < 2*HH) { be += ldf(ebhh, i, f); bd += ldf(dbhh, i, f); }
    cbe[i] = be; cbd[i] = bd;
  }
  for (int i = tid; i < OUTV; i += nth) obf[i] = ldf(outb, i, f);
  for (int i = tid; i < 2*QW_PER_BUF; i += nth) hq[i] = 0ull;  // tag0 + h=0
}

// ---------------------------------------------------------------------------
// Generic MFMA GEMM: C[m][n] = sum_k A[m][k]*B[n][k] (+bias[n]), K=256 fixed.
// tshift!=0: output rows remapped m=(b*T+t) -> t*BB+b with T=1<<tshift.
// a_f32!=0: ws A operand is fp32 (converted to bf16 during staging).
// bias (if non-null) is always fp32 (prep-produced).
// ---------------------------------------------------------------------------
#define LDT 264

__global__ __launch_bounds__(256) void gemm_kernel(
    const ushort_t* A, const int* tokens, const void* emb,
    const void* Bw, int ldb, int b_off,
    const float* bias, const uint_t* flagp,
    float* Cf, ushort_t* Cb, int ldc, int M, int tshift, int a_f32) {
  __shared__ __align__(16) ushort_t Bs[64*LDT];
  __shared__ __align__(16) ushort_t As[32*LDT];
  uint_t f = *flagp;
  int tid = threadIdx.x;
  int wave = tid >> 6, lane = tid & 63;
  int n0 = blockIdx.x * 64;
#pragma unroll
  for (int it = 0; it < 8; ++it) {
    int idx = it*256 + tid;
    int row = idx >> 5, col = (idx & 31) << 3;
    size_t e = (size_t)(n0 + row)*ldb + col + b_off;
    uint4 v;
    if (f) {
      const float4* s = (const float4*)((const float*)Bw + e);
      float4 x = s[0], y = s[1];
      v.x = (uint_t)f2b(x.x) | ((uint_t)f2b(x.y) << 16);
      v.y = (uint_t)f2b(x.z) | ((uint_t)f2b(x.w) << 16);
      v.z = (uint_t)f2b(y.x) | ((uint_t)f2b(y.y) << 16);
      v.w = (uint_t)f2b(y.z) | ((uint_t)f2b(y.w) << 16);
    } else {
      v = *(const uint4*)((const ushort_t*)Bw + e);
    }
    *(uint4*)(Bs + row*LDT + col) = v;
  }
  int arow_i = lane & 15;
  float bias_v = 0.f;
  if (bias) bias_v = bias[n0 + wave*16 + arow_i];
  int koff = (lane >> 4) << 3;
  for (int m0 = blockIdx.y*32; m0 < M; m0 += gridDim.y*32) {
    __syncthreads();   // Bs ready / previous chunk compute done
#pragma unroll
    for (int it = 0; it < 4; ++it) {
      int idx = it*256 + tid;
      int row = idx >> 5, col = (idx & 31) << 3;
      uint4 v;
      if (tokens) {
        size_t e = (size_t)tokens[m0 + row]*KK + col;
        if (f) {
          const float4* s = (const float4*)((const float*)emb + e);
          float4 x = s[0], y = s[1];
          v.x = (uint_t)f2b(x.x) | ((uint_t)f2b(x.y) << 16);
          v.y = (uint_t)f2b(x.z) | ((uint_t)f2b(x.w) << 16);
          v.z = (uint_t)f2b(y.x) | ((uint_t)f2b(y.y) << 16);
          v.w = (uint_t)f2b(y.z) | ((uint_t)f2b(y.w) << 16);
        } else {
          v = *(const uint4*)((const ushort_t*)emb + e);
        }
      } else if (a_f32) {
        const float4* s = (const float4*)((const float*)A + (size_t)(m0 + row)*KK + col);
        float4 x = s[0], y = s[1];
        v.x = (uint_t)f2b(x.x) | ((uint_t)f2b(x.y) << 16);
        v.y = (uint_t)f2b(x.z) | ((uint_t)f2b(x.w) << 16);
        v.z = (uint_t)f2b(y.x) | ((uint_t)f2b(y.y) << 16);
        v.w = (uint_t)f2b(y.z) | ((uint_t)f2b(y.w) << 16);
      } else {
        v = *(const uint4*)(A + (size_t)(m0 + row)*KK + col);  // ws bf16
      }
      *(uint4*)(As + row*LDT + col) = v;
    }
    __syncthreads();
#pragma unroll
    for (int msub = 0; msub < 2; ++msub) {
      f32x4 acc = {0.f,0.f,0.f,0.f};
      const ushort_t* ap = As + (msub*16 + arow_i)*LDT + koff;
      const ushort_t* bp = Bs + (wave*16 + arow_i)*LDT + koff;
#pragma unroll
      for (int ks = 0; ks < 8; ++ks) {
        short8 af = *(const short8*)(ap + ks*32);
        short8 bf = *(const short8*)(bp + ks*32);
        acc = __builtin_amdgcn_mfma_f32_16x16x32_bf16(af, bf, acc, 0, 0, 0);
      }
      int mbase = m0 + msub*16 + (lane >> 4)*4;
      int ncol = n0 + wave*16 + arow_i;
#pragma unroll
      for (int r = 0; r < 4; ++r) {
        float val = acc[r] + bias_v;
        int mr = mbase + r;
        int orow = tshift ? (((mr & ((1 << tshift) - 1)) << 4) + (mr >> tshift)) : mr;
        if (Cf) Cf[(size_t)orow*ldc + ncol] = val;
        else    Cb[(size_t)orow*ldc + ncol] = f2b(val);
      }
    }
  }
}

// ---------------------------------------------------------------------------
// Multi-CU MFMA GRU (UNCHANGED from round 6 -- 330 us, do not perturb).
// Tagged-word h exchange with coalesced layout; see round-6 notes.
// ---------------------------------------------------------------------------
#define HSBF 264            // LDS row stride (bf16 elems): <=2-way banks on b128

__device__ __forceinline__ void stage_w(const ushort_t* WB, int j0, int tid,
                                        ushort_t* wlds) {
#pragma unroll
  for (int it = 0; it < 6; ++it) {
    int idx = it*256 + tid;
    int row = idx >> 5, col = (idx & 31) << 3;   // row 0..47, col 0..255 step 8
    const ushort_t* src = WB + ((size_t)((row >> 4)*HH + j0 + (row & 15)))*KK + col;
    *(uint4*)(wlds + row*HSBF + col) = *(const uint4*)src;
  }
}

__global__ __launch_bounds__(256) void gru_kernel(
    const float* gi_e, const float* gi_d, const ushort_t* WBe, const ushort_t* WBd,
    const void* ebhh, const void* dbhh, const uint_t* flagp,
    const int* elen, const int* dlen, float* eout, float* dout, u64_t* hq) {
  uint_t f = *flagp;
  __shared__ __align__(16) ushort_t wlds[48*HSBF];        // 24.75 KB
  __shared__ __align__(16) float part[2][4][3][16][17];   // 25.5 KB parity-dbuf
  const int tid = threadIdx.x;
  const int wave = tid >> 6, lane = tid & 63;
  const int mrow = lane & 15, quad = lane >> 4;           // MFMA fragment coords
  const int j0 = blockIdx.x * JD;
  const int m = tid >> 4, n = tid & 15;                   // elementwise coords
  const int j = j0 + n;
  // permuted publish index for this thread's (even) pair base j & ~1:
  const int je = j & ~1;
  const int widx = ((je >> 6) << 9) + (((je >> 5) & 1) << 8)
                 + (((je >> 1) & 3) << 6) + (((je >> 3) & 3) << 4) + m;

  stage_w(WBe, j0, tid, wlds);
  const float bn_e = ldf(ebhh, 2*HH + j, f);
  const float bn_d = ldf(dbhh, 2*HH + j, f);
  const int len_e = elen[m], len_d = dlen[m];
  float hreg = 0.f;
  // prefetch gi for s=0 (rows are (t,b)-interleaved: (t*BB+m))
  float grv = gi_e[(size_t)m*G3 + j];
  float gzv = gi_e[(size_t)m*G3 + HH + j];
  float gnv = gi_e[(size_t)m*G3 + 2*HH + j];
  __syncthreads();   // weights staged

  for (int s = 0; s < TE + TD; ++s) {
    if (s == TE) {   // encoder->decoder: restage weights. All threads passed
                     // step TE-1's mid-step sync (after their last wlds MFMA
                     // reads); EW phase never touches wlds. Sync after.
      stage_w(WBd, j0, tid, wlds);
      __syncthreads();
    }
    const bool enc = s < TE;
    const int t = enc ? s : s - TE;
    // ---- poll own wave's 8 tagged qwords (coalesced layout) --------------
    const u64_t* hbR = hq + (size_t)(s & 1)*QW_PER_BUF + wave*512 + lane;
    u64_t qv[8];
    const uint_t target = (uint_t)s;
    int guard = 0;
    for (;;) {
      bool ok = true;
#pragma unroll
      for (int ks = 0; ks < 2; ++ks)
#pragma unroll
        for (int i = 0; i < 4; ++i) {
          qv[ks*4 + i] = __hip_atomic_load(hbR + ks*256 + i*64,
                                           __ATOMIC_RELAXED, __HIP_MEMORY_SCOPE_AGENT);
          ok = ok && ((uint_t)qv[ks*4 + i] == target);
        }
      if (__all(ok) || ++guard > 30000) break;   // bounded (r3 lesson)
    }
    // ---- MFMA: 3 gate tiles, wave's K-slice = [64*wave, 64*wave+64) ------
    f32x4 ar = {0.f,0.f,0.f,0.f}, az = {0.f,0.f,0.f,0.f}, an = {0.f,0.f,0.f,0.f};
#pragma unroll
    for (int ks = 0; ks < 2; ++ks) {
      union { uint_t u[4]; short8 s8; } av;
#pragma unroll
      for (int i = 0; i < 4; ++i) av.u[i] = (uint_t)(qv[ks*4 + i] >> 32);
      const ushort_t* wp = wlds + mrow*HSBF + wave*64 + ks*32 + quad*8;
      short8 b0 = *(const short8*)(wp);
      short8 b1 = *(const short8*)(wp + 16*HSBF);
      short8 b2 = *(const short8*)(wp + 32*HSBF);
      ar = __builtin_amdgcn_mfma_f32_16x16x32_bf16(av.s8, b0, ar, 0, 0, 0);
      az = __builtin_amdgcn_mfma_f32_16x16x32_bf16(av.s8, b1, az, 0, 0, 0);
      an = __builtin_amdgcn_mfma_f32_16x16x32_bf16(av.s8, b2, an, 0, 0, 0);
    }
    // ---- partial store: C-frag row=quad*4+r (m), col=mrow (n) -------------
    const int p = s & 1;
#pragma unroll
    for (int r = 0; r < 4; ++r) {
      part[p][wave][0][quad*4 + r][mrow] = ar[r];
      part[p][wave][1][quad*4 + r][mrow] = az[r];
      part[p][wave][2][quad*4 + r][mrow] = an[r];
    }
    __syncthreads();   // the ONLY per-step block barrier
    // ---- reduce K-partials + elementwise (thread owns (m, j)) ------------
    float accr = 0.f, accz = 0.f, accn = 0.f;
#pragma unroll
    for (int w = 0; w < 4; ++w) {
      accr += part[p][w][0][m][n];
      accz += part[p][w][1][m][n];
      accn += part[p][w][2][m][n];
    }
    float rr = fsig(grv + accr);                    // bih+bhh pre-folded in gi
    float zz = fsig(gzv + accz);
    float nn = ftanh(gnv + rr*(accn + (enc ? bn_e : bn_d)));
    float hc = (1.f - zz)*nn + zz*hreg;
    bool valid = t < (enc ? len_e : len_d);
    float ov = valid ? hc : 0.f;
    hreg = valid ? hc : hreg;
    if (enc) eout[((size_t)(m*TE + t))*HH + j] = ov;
    else     dout[((size_t)(m*TD + t))*HH + j] = ov;
    // ---- publish tagged h qword (even n lanes), fire-and-forget ----------
    uint_t h16 = (uint_t)f2b(hreg);
    uint_t up = (uint_t)__shfl_down((int)h16, 1);
    if (!(n & 1)) {
      u64_t q = ((u64_t)(h16 | (up << 16)) << 32) | (u64_t)(uint_t)(s + 1);
      __hip_atomic_store(hq + (size_t)((s + 1) & 1)*QW_PER_BUF + widx,
                         q, __ATOMIC_RELAXED, __HIP_MEMORY_SCOPE_AGENT);
    }
    // ---- prefetch next step's gi (overlaps next poll) --------------------
    int s2 = s + 1;
    if (s2 < TE + TD) {
      const float* g2 = (s2 < TE) ? (gi_e + (size_t)(s2*BB + m)*G3)
                                  : (gi_d + (size_t)((s2 - TE)*BB + m)*G3);
      grv = g2[j]; gzv = g2[HH + j]; gnv = g2[2*HH + j];
    }
  }
}

// ---------------------------------------------------------------------------
// Attention + dense, one block per (b, td). (round-7 rewrite, resubmitted
// verbatim -- round-7 bench died to an infra flake, not a kernel fault):
//  * libm tanhf -> ftanh (__expf-based, ~5x cheaper).
//  * energy/context loops over the valid prefix te < el only; whole phase
//    skipped for invalid td (dok is block-uniform).
//  * context: branchless, 4 independent accumulators (loads pipeline).
//  * dense: 4 accumulators, unroll 8 (breaks 512-deep serial fma chain).
// ---------------------------------------------------------------------------
__global__ __launch_bounds__(256) void attn_kernel(
    const float* eprj, const float* dprj, const float* eout, const float* dout,
    const void* Wb, const void* av, const void* avb,
    const ushort_t* DWT, const void* db, const uint_t* flagp,
    const int* elen, const int* dlen, ushort_t* dense_bf) {
  int bd = blockIdx.x;
  int b = bd / TD, td = bd % TD;
  int tid = threadIdx.x;
  int wave = tid >> 6, lane = tid & 63;
  uint_t f = *flagp;
  __shared__ float dp[HH], dsrow[HH], vv[HH], att[TE];
  int el = elen[b];
  bool dok = td < dlen[b];   // uniform per block
  size_t drow = (size_t)bd * HH;
  dp[tid] = dprj[drow + tid] + ldf(Wb, tid, f);
  dsrow[tid] = dout[drow + tid];
  vv[tid] = ldf(av, tid, f);
  if (tid < TE) att[tid] = 0.f;    // weights default 0 (te >= el / invalid td)
  __syncthreads();
  float ctx = 0.f;
  if (dok) {
    float vb0 = ldf(avb, 0, f);
    // ---- energies for te < el, wave-strided ------------------------------
    int nteb = (el + 3) >> 2;
    for (int teb = 0; teb < nteb; ++teb) {
      int te = teb*4 + wave;          // wave-uniform
      if (te < el) {
        const float* ep = eprj + (size_t)(b*TE + te)*HH;
        float s = 0.f;
#pragma unroll
        for (int i = 0; i < 4; ++i) {
          int hh = lane + 64*i;
          s += ftanh(ep[hh] + dp[hh]) * vv[hh];
        }
#pragma unroll
        for (int off = 32; off > 0; off >>= 1) s += __shfl_xor(s, off);
        if (lane == 0) att[te] = s + vb0;
      }
    }
    __syncthreads();
    // ---- softmax over valid prefix --------------------------------------
    float mx = -1e30f;
    for (int te = 0; te < el; ++te) mx = fmaxf(mx, att[te]);
    __syncthreads();                 // all reads of raw energies done
    if (tid < el) att[tid] = __expf(att[tid] - mx);
    __syncthreads();
    float ssum = 0.f;
    for (int te = 0; te < el; ++te) ssum += att[te];
    float inv = (ssum > 0.f) ? 1.f/ssum : 0.f;
    // ---- context: branchless, 4 accumulators -----------------------------
    const float* ebase = eout + (size_t)(b*TE)*HH + tid;
    float c0 = 0.f, c1 = 0.f, c2 = 0.f, c3 = 0.f;
    int te = 0;
    for (; te + 4 <= el; te += 4) {
      c0 += att[te    ] * ebase[(size_t)(te    )*HH];
      c1 += att[te + 1] * ebase[(size_t)(te + 1)*HH];
      c2 += att[te + 2] * ebase[(size_t)(te + 2)*HH];
      c3 += att[te + 3] * ebase[(size_t)(te + 3)*HH];
    }
    for (; te < el; ++te) c0 += att[te] * ebase[(size_t)te*HH];
    ctx = (c0 + c1 + c2 + c3) * inv;
  }
  __syncthreads();                   // att/dp reads done before dp reuse
  dp[tid] = ctx;                     // reuse dp as context
  __syncthreads();
  // ---- dense: acc = b + dsrow@W1col + ctx@W2col, 4 accumulators ----------
  const ushort_t* w0 = DWT + tid;
  float a0 = ldf(db, tid, f), a1 = 0.f, a2 = 0.f, a3 = 0.f;
#pragma unroll 8
  for (int k = 0; k < HH; k += 4) {
    a0 = fmaf(b2f(w0[(size_t)(k    )*HH]), dsrow[k    ], a0);
    a1 = fmaf(b2f(w0[(size_t)(k + 1)*HH]), dsrow[k + 1], a1);
    a2 = fmaf(b2f(w0[(size_t)(k + 2)*HH]), dsrow[k + 2], a2);
    a3 = fmaf(b2f(w0[(size_t)(k + 3)*HH]), dsrow[k + 3], a3);
  }
#pragma unroll 8
  for (int k = 0; k < HH; k += 4) {
    a0 = fmaf(b2f(w0[(size_t)(HH + k    )*HH]), dp[k    ], a0);
    a1 = fmaf(b2f(w0[(size_t)(HH + k + 1)*HH]), dp[k + 1], a1);
    a2 = fmaf(b2f(w0[(size_t)(HH + k + 2)*HH]), dp[k + 2], a2);
    a3 = fmaf(b2f(w0[(size_t)(HH + k + 3)*HH]), dp[k + 3], a3);
  }
  dense_bf[drow + tid] = f2b(ftanh(a0 + a1 + a2 + a3));
}

// ---------------------------------------------------------------------------
extern "C" void kernel_launch(void* const* d_in, const int* in_sizes, int n_in,
                              void* d_out, int out_size, void* d_ws, size_t ws_size,
                              hipStream_t stream) {
  const int* enc_in   = (const int*)d_in[0];
  const int* enc_len  = (const int*)d_in[1];
  const int* dec_in   = (const int*)d_in[2];
  const int* dec_len  = (const int*)d_in[3];
  const void* emb    = d_in[4];
  const void* eWih   = d_in[5];
  const void* eWhh   = d_in[6];
  const void* ebih   = d_in[7];
  const void* ebhh   = d_in[8];
  const void* dWih   = d_in[9];
  const void* dWhh   = d_in[10];
  const void* dbih   = d_in[11];
  const void* dbhh   = d_in[12];
  const void* attnW  = d_in[13];
  const void* attnWb = d_in[14];
  const void* attnv  = d_in[15];
  const void* attnvb = d_in[16];
  const void* denseW = d_in[17];
  const void* denseb = d_in[18];
  const void* outW   = d_in[19];
  const void* outb   = d_in[20];
  float* out = (float*)d_out;   // reference output is fp32

  float* ws = (float*)d_ws;
  size_t o = 0;
  uint_t* flag = (uint_t*)(ws + o);   o += 4;
  u64_t* hq = (u64_t*)(ws + o);       o += 4*QW_PER_BUF;  // 2 bufs x 2048 qwords
  ushort_t* WBe = (ushort_t*)(ws + o); o += G3*KK/2;
  ushort_t* WBd = (ushort_t*)(ws + o); o += G3*KK/2;
  ushort_t* DWT = (ushort_t*)(ws + o); o += 512*HH/2;
  float* cbe = ws + o;                o += G3;
  float* cbd = ws + o;                o += G3;
  float* obf = ws + o;                o += OUTV;
  float* gi_e = ws + o;               o += (size_t)MROWS_E*G3;   // (t,b)-interleaved
  float* gi_d = ws + o;               o += (size_t)MROWS_D*G3;   // (t,b)-interleaved
  float* eout = ws + o;               o += (size_t)MROWS_E*HH;
  float* dout = ws + o;               o += (size_t)MROWS_D*HH;
  float* eprj = ws + o;               o += (size_t)MROWS_E*HH;
  float* dprj = ws + o;               o += (size_t)MROWS_D*HH;
  ushort_t* dense_bf = (ushort_t*)(ws + o); o += (size_t)MROWS_D*HH/2;

  detect_kernel<<<1, 256, 0, stream>>>(emb, flag);
  prep_kernel<<<384, 256, 0, stream>>>(eWhh, dWhh, denseW, ebih, ebhh, dbih, dbhh,
                                       outb, flag, WBe, WBd, DWT, cbe, cbd, obf, hq);
  // gi = emb[tokens] @ Wih.T + (bih + bhh[r,z]), rows (t,b)-interleaved
  gemm_kernel<<<dim3(12,8), 256, 0, stream>>>(nullptr, enc_in, emb, eWih, 256, 0,
                                              cbe, flag, gi_e, nullptr, G3, MROWS_E, 7, 0);
  gemm_kernel<<<dim3(12,4), 256, 0, stream>>>(nullptr, dec_in, emb, dWih, 256, 0,
                                              cbd, flag, gi_d, nullptr, G3, MROWS_D, 6, 0);
  gru_kernel<<<NBLK, 256, 0, stream>>>(gi_e, gi_d, WBe, WBd, ebhh, dbhh, flag,
                                       enc_len, dec_len, eout, dout, hq);
  // enc_proj = enc_out @ W1.T ; dec_proj = dec_out @ W2.T  (attn_W col split)
  gemm_kernel<<<dim3(4,16), 256, 0, stream>>>((const ushort_t*)eout, nullptr, nullptr,
                                              attnW, 512, 0, nullptr, flag, eprj,
                                              nullptr, HH, MROWS_E, 0, 1);
  gemm_kernel<<<dim3(4,8), 256, 0, stream>>>((const ushort_t*)dout, nullptr, nullptr,
                                             attnW, 512, 256, nullptr, flag, dprj,
                                             nullptr, HH, MROWS_D, 0, 1);
  attn_kernel<<<MROWS_D, 256, 0, stream>>>(eprj, dprj, eout, dout, attnWb, attnv, attnvb,
                                           DWT, denseb, flag, enc_len, dec_len, dense_bf);
  // logits = dense @ out_W.T + out_b  (fp32 out)
  gemm_kernel<<<dim3(500,4), 256, 0, stream>>>(dense_bf, nullptr, nullptr, outW, 256, 0,
                                               obf, flag, out, nullptr, OUTV, MROWS_D, 0, 0);
}